// Round 10
// baseline (2476.009 us; speedup 1.0000x reference)
//
#include <hip/hip_runtime.h>
#include <stdint.h>

#define B_ 16
#define S_ 512
#define H_ 768
#define L_ 12
#define NH_ 12
#define DH_ 64
#define FF_ 3072
#define WD_ 256
#define W_ 255
#define MTOK_ (B_*S_)
#define QKVN_ 2304
#define MPADR_ 128   // dummy pad rows appended to row-indexed buffers

typedef _Float16 f16;
typedef _Float16 f16x8 __attribute__((ext_vector_type(8)));
typedef _Float16 f16x4 __attribute__((ext_vector_type(4)));
typedef _Float16 f16x2 __attribute__((ext_vector_type(2)));
typedef float f32x4 __attribute__((ext_vector_type(4)));

#define SCHED_FENCE() __builtin_amdgcn_sched_barrier(0)

// tanh-form gelu via exp-sigmoid; max |dev| vs exact ~7e-4 (threshold margin 3x)
__device__ __forceinline__ float gelu_fast(float x) {
  float u = x * (1.0f + 0.044715f * x * x);
  float e = __expf(-1.5957691216f * u);
  return __fdividef(x, 1.0f + e);
}

__device__ __forceinline__ void gload16(const f16* g, f16* l) {
  __builtin_amdgcn_global_load_lds(
      (const __attribute__((address_space(1))) void*)g,
      (__attribute__((address_space(3))) void*)l, 16, 0, 0);
}

// Row-compacted GEMM, counted-vmcnt 2-deep pipeline. BM=BN=128 -> 64x64 wave
// tiles (8 ds_read_b128 : 16 MFMA, ratio 0.5 = m97 geometry). SPLITK>1:
// blockIdx.z selects K-chunk; chunk z writes Cv + z*czoff (f16), bias only z=0.
template<int BM, int BN, int ACT, int OUTF16, int BIAS, int QKVW, int SPLITK>
__global__ __launch_bounds__(256) void gemm2_k(
    const f16* __restrict__ A, const f16* __restrict__ Bm, void* __restrict__ Cv,
    const float* __restrict__ bias, f16* __restrict__ vTp,
    const int* __restrict__ rowmap, const int* __restrict__ meta,
    int lda, int ldb, int ldc, int K, float scale, long czoff)
{
  constexpr int MI = BM / 32;
  constexpr int NI = BN / 32;
  constexpr int LPW = BM / 32 + BN / 32;    // own gload16s per stage per wave
  const int gx = gridDim.x;
  int flat = blockIdx.y * gx + blockIdx.x;
  const int nlive = (meta[1] / BM) * gx;
  if (flat >= nlive) return;                // uniform: whole block exits pre-barrier
  {
    int q = nlive >> 3, r = nlive & 7;
    int xcd = flat & 7, idx = flat >> 3;
    flat = (xcd < r ? xcd * (q + 1) : r * (q + 1) + (xcd - r) * q) + idx;
  }
  const int row0 = (flat / gx) * BM;
  const int col0 = (flat % gx) * BN;
  const int z = (SPLITK > 1) ? blockIdx.z : 0;
  const int kc_len = K / SPLITK;
  A  += (size_t)z * kc_len;                 // column offset into A
  Bm += (size_t)z * kc_len;

  __shared__ __align__(16) f16 lA[2][BM * 64];
  __shared__ __align__(16) f16 lB[2][BN * 64];
  const int lane = threadIdx.x & 63;
  const int wave = threadIdx.x >> 6;
  const int wr = wave >> 1, wc = wave & 1;
  const int srow = lane >> 3;
  const int scol = lane & 7;
  const int cs = scol ^ srow;

  int arow[BM / 32];
#pragma unroll
  for (int i = 0; i < BM / 32; ++i)
    arow[i] = rowmap[row0 + (wave * (BM / 32) + i) * 8 + srow];

  auto stage = [&](int p, int k0) {
#pragma unroll
    for (int i = 0; i < BM / 32; ++i) {
      int seg = wave * (BM / 32) + i;
      gload16(&A[(size_t)arow[i] * lda + k0 + cs * 8], &lA[p][seg * 512]);
    }
#pragma unroll
    for (int i = 0; i < BN / 32; ++i) {
      int seg = wave * (BN / 32) + i;
      gload16(&Bm[(size_t)(col0 + seg * 8 + srow) * ldb + k0 + cs * 8], &lB[p][seg * 512]);
    }
  };

  f32x4 acc[MI][NI] = {};
  const int nt = kc_len >> 6;
  const int rl = lane & 15, g = lane >> 4;
  stage(0, 0);
  if (nt > 1) stage(1, 64);
  for (int t = 0; t < nt; ++t) {
    // B1: own stage(t) retired (stage(t+1) may remain in flight), then sync.
    if (t < nt - 1) { asm volatile("s_waitcnt vmcnt(%0) lgkmcnt(0)" :: "i"(LPW) : "memory"); }
    else            { asm volatile("s_waitcnt vmcnt(0) lgkmcnt(0)" ::: "memory"); }
    SCHED_FENCE();
    __builtin_amdgcn_s_barrier();
    SCHED_FENCE();
    const int p = t & 1;
    __builtin_amdgcn_s_setprio(1);
#pragma unroll
    for (int c = 0; c < 2; ++c) {
      f16x8 af[MI], bf[NI];
#pragma unroll
      for (int mi = 0; mi < MI; ++mi) {
        int r = wr * (MI * 16) + mi * 16 + rl;
        int u = (c * 4 + g) ^ (r & 7);
        af[mi] = *(const f16x8*)&lA[p][r * 64 + u * 8];
      }
#pragma unroll
      for (int ni = 0; ni < NI; ++ni) {
        int r = wc * (NI * 16) + ni * 16 + rl;
        int u = (c * 4 + g) ^ (r & 7);
        bf[ni] = *(const f16x8*)&lB[p][r * 64 + u * 8];
      }
#pragma unroll
      for (int mi = 0; mi < MI; ++mi)
#pragma unroll
        for (int ni = 0; ni < NI; ++ni)
          acc[mi][ni] = __builtin_amdgcn_mfma_f32_16x16x32_f16(af[mi], bf[ni], acc[mi][ni], 0, 0, 0);
    }
    __builtin_amdgcn_s_setprio(0);
    SCHED_FENCE();
    // B2: all waves done reading buf[t&1] -> safe to overwrite with stage(t+2)
    asm volatile("s_waitcnt lgkmcnt(0)" ::: "memory");
    SCHED_FENCE();
    __builtin_amdgcn_s_barrier();
    SCHED_FENCE();
    if (t + 2 < nt) stage(p, (t + 2) * 64);
  }
  // epilogue: C/D layout col=lane&15, row=(lane>>4)*4+reg; rows via rowmap
  const int cl = lane & 15;
  const int rq = (lane >> 4) * 4;
#pragma unroll
  for (int mi = 0; mi < MI; ++mi) {
    const int4 rm4 = *(const int4*)&rowmap[row0 + wr * (MI * 16) + mi * 16 + rq];
    const int rows[4] = { rm4.x, rm4.y, rm4.z, rm4.w };
    const bool contig = (rm4.w == rm4.x + 3) && ((rm4.x & 3) == 0);
#pragma unroll
    for (int ni = 0; ni < NI; ++ni) {
      int col = col0 + wc * (NI * 16) + ni * 16 + cl;
      float bv = 0.f;
      if constexpr (BIAS) { if (SPLITK == 1 || z == 0) bv = bias[col]; }
      if constexpr (QKVW) {
        if (col >= 2 * H_) {                 // transposed V write: vT[bh][d][s]
          int vc = col - 2 * H_;
          int h = vc >> 6, d = vc & 63;
          if (contig) {
            if (rm4.x < MTOK_) {
              int b = rm4.x >> 9, s = rm4.x & (S_ - 1);
              f16x4 o4;
#pragma unroll
              for (int r = 0; r < 4; ++r) o4[r] = (f16)(acc[mi][ni][r] * scale + bv);
              *(f16x4*)&vTp[(((size_t)(b * NH_ + h)) * DH_ + d) * S_ + s] = o4;
            }
          } else {
#pragma unroll
            for (int r = 0; r < 4; ++r) {
              int orow = rows[r];
              if (orow < MTOK_) {
                int b = orow >> 9, s = orow & (S_ - 1);
                vTp[(((size_t)(b * NH_ + h)) * DH_ + d) * S_ + s] = (f16)(acc[mi][ni][r] * scale + bv);
              }
            }
          }
          continue;
        }
      }
#pragma unroll
      for (int r = 0; r < 4; ++r) {
        float v = acc[mi][ni][r] * scale + bv;
        if constexpr (ACT == 1) v = gelu_fast(v);
        if constexpr (OUTF16) {
          ((f16*)Cv + (size_t)z * czoff)[(size_t)rows[r] * ldc + col] = (f16)v;
        } else {
          ((float*)Cv)[(size_t)rows[r] * ldc + col] = v;
        }
      }
    }
  }
}

// Fused flash attention with issue-early staging + counted vmcnt (1-ahead).
// grid (b*NH, qtile): dead q-tiles form the dispatch tail -> XCD-balanced.
// Swapped QK^T -> S^T acc. No-max softmax (scores O(1), shift-invariant;
// masked kv -> exact 0).
__global__ __launch_bounds__(256) void fattn_k(
    const f16* __restrict__ qkv, const f16* __restrict__ vT,
    f16* __restrict__ ctx, const int* __restrict__ lenp)
{
  const int bh = blockIdx.x, qt = blockIdx.y;
  const int b = bh / NH_, h = bh - b * NH_;
  const int L = lenp[b];
  if ((qt << 7) >= L) return;               // uniform per block
  const int nkt = (L + 63) >> 6;
  const int lane = threadIdx.x & 63, wave = threadIdx.x >> 6;
  const int rl = lane & 15, g = lane >> 4;
  const int srow = lane >> 3, scol = lane & 7;
  const int cs = scol ^ srow;

  __shared__ __align__(16) f16 lK[2][64 * 64];
  __shared__ __align__(16) f16 lV[2][64 * 64];
  __shared__ __align__(16) f16 lP[128 * 72];

  auto stage = [&](int p, int kt) {       // 4 gload16 per wave
#pragma unroll
    for (int i = 0; i < 2; ++i) {
      int seg = wave * 2 + i;
      int r = seg * 8 + srow;
      gload16(&qkv[((size_t)b * S_ + kt * 64 + r) * QKVN_ + H_ + h * DH_ + cs * 8], &lK[p][seg * 512]);
      gload16(&vT[((size_t)bh * DH_ + r) * S_ + kt * 64 + cs * 8], &lV[p][seg * 512]);
    }
  };

  const size_t qrow0 = (size_t)b * S_ + qt * 128 + wave * 32;
  f16x8 qf[2][2];
#pragma unroll
  for (int bq = 0; bq < 2; ++bq)
#pragma unroll
    for (int kc = 0; kc < 2; ++kc)
      qf[bq][kc] = *(const f16x8*)&qkv[(qrow0 + bq * 16 + rl) * QKVN_ + h * DH_ + kc * 32 + g * 8];

  float lsum[2] = {0.f, 0.f};
  f32x4 accO[2][4] = {};

  stage(0, 0);
  for (int kt = 0; kt < nkt; ++kt) {
    // issue next stage BEFORE waiting; buf^1 reads finished at prev B2
    if (kt + 1 < nkt) {
      stage((kt + 1) & 1, kt + 1);
      asm volatile("s_waitcnt vmcnt(4) lgkmcnt(0)" ::: "memory");
    } else {
      asm volatile("s_waitcnt vmcnt(0) lgkmcnt(0)" ::: "memory");
    }
    SCHED_FENCE();
    __builtin_amdgcn_s_barrier();           // B1: all stage(kt) complete
    SCHED_FENCE();
    const int p = kt & 1;

    f32x4 accS[4][2] = {};
    __builtin_amdgcn_s_setprio(1);
#pragma unroll
    for (int kc = 0; kc < 2; ++kc) {
#pragma unroll
      for (int ak = 0; ak < 4; ++ak) {
        int row = ak * 16 + rl;
        int u = (kc * 4 + g) ^ (row & 7);
        f16x8 kf = *(const f16x8*)&lK[p][row * 64 + u * 8];
#pragma unroll
        for (int bq = 0; bq < 2; ++bq)
          accS[ak][bq] = __builtin_amdgcn_mfma_f32_16x16x32_f16(kf, qf[bq][kc], accS[ak][bq], 0, 0, 0);
      }
    }
    __builtin_amdgcn_s_setprio(0);

    const int kvb = kt * 64 + g * 4;
#pragma unroll
    for (int bq = 0; bq < 2; ++bq) {
      float pv[16];
      float ps = 0.f;
#pragma unroll
      for (int ak = 0; ak < 4; ++ak)
#pragma unroll
        for (int r = 0; r < 4; ++r) {
          float s = accS[ak][bq][r] * 0.125f;
          float pp = (kvb + ak * 16 + r < L) ? __expf(s) : 0.f;
          pv[ak * 4 + r] = pp;
          ps += pp;
        }
      ps += __shfl_xor(ps, 16);
      ps += __shfl_xor(ps, 32);
      lsum[bq] += ps;
      const int qrow = wave * 32 + bq * 16 + rl;
#pragma unroll
      for (int ak = 0; ak < 4; ++ak)
#pragma unroll
        for (int r2 = 0; r2 < 2; ++r2) {
          f16x2 pk = { (f16)pv[ak * 4 + r2 * 2], (f16)pv[ak * 4 + r2 * 2 + 1] };
          *(f16x2*)&lP[qrow * 72 + ak * 16 + g * 4 + r2 * 2] = pk;
        }
    }
    __builtin_amdgcn_s_setprio(1);
#pragma unroll
    for (int kc = 0; kc < 2; ++kc) {
      f16x8 pa[2], vf[4];
#pragma unroll
      for (int aq = 0; aq < 2; ++aq) {
        int prow = wave * 32 + aq * 16 + rl;
        pa[aq] = *(const f16x8*)&lP[prow * 72 + kc * 32 + g * 8];
      }
#pragma unroll
      for (int bd = 0; bd < 4; ++bd) {
        int vrow = bd * 16 + rl;
        int u = (kc * 4 + g) ^ (vrow & 7);
        vf[bd] = *(const f16x8*)&lV[p][vrow * 64 + u * 8];
      }
#pragma unroll
      for (int aq = 0; aq < 2; ++aq)
#pragma unroll
        for (int bd = 0; bd < 4; ++bd)
          accO[aq][bd] = __builtin_amdgcn_mfma_f32_16x16x32_f16(pa[aq], vf[bd], accO[aq][bd], 0, 0, 0);
    }
    __builtin_amdgcn_s_setprio(0);
    SCHED_FENCE();
    asm volatile("s_waitcnt lgkmcnt(0)" ::: "memory");
    SCHED_FENCE();
    __builtin_amdgcn_s_barrier();           // B2: all reads of buf[kt&1] done
    SCHED_FENCE();
  }

  float linv[2] = { 1.f / lsum[0], 1.f / lsum[1] };
  const size_t orow0 = (size_t)b * S_ + qt * 128 + wave * 32;
#pragma unroll
  for (int aq = 0; aq < 2; ++aq)
#pragma unroll
    for (int r = 0; r < 4; ++r) {
      float li = __shfl(linv[aq], (lane & 48) | (g * 4 + r));
      int q = aq * 16 + g * 4 + r;
#pragma unroll
      for (int bd = 0; bd < 4; ++bd)
        ctx[(orow0 + q) * H_ + h * DH_ + bd * 16 + rl] = (f16)(accO[aq][bd][r] * li);
    }
}

// out[n*ldout + k] = (f16) in[k*ldin + n]; 32x32 tiles, batched via z.
template<typename TI>
__global__ __launch_bounds__(256) void transpose_f16_k(
    const TI* __restrict__ in, f16* __restrict__ out,
    int ldin, int ldout, long i1, long o1)
{
  const int z = blockIdx.z;
  in  += (size_t)z * i1;
  out += (size_t)z * o1;
  __shared__ float t[32][33];
  const int kt = blockIdx.y * 32, nt = blockIdx.x * 32;
  const int tx = threadIdx.x & 31, tg = threadIdx.x >> 5;
#pragma unroll
  for (int i = 0; i < 4; ++i) {
    int k = tg * 4 + i;
    t[k][tx] = (float)in[(size_t)(kt + k) * ldin + nt + tx];
  }
  __syncthreads();
#pragma unroll
  for (int i = 0; i < 4; ++i) {
    int n = tg * 4 + i;
    out[(size_t)(nt + n) * ldout + kt + tx] = (f16)t[tx][n];
  }
}

__global__ void bias_cat_k(const float* __restrict__ bq, const float* __restrict__ bk,
                           const float* __restrict__ bv, float* __restrict__ out) {
  const int l = blockIdx.y;
  const int j = blockIdx.x * 256 + threadIdx.x;
  float v = (j < H_) ? bq[l * H_ + j] : (j < 2 * H_) ? bk[l * H_ + j - H_] : bv[l * H_ + j - 2 * H_];
  out[l * QKVN_ + j] = v;
}

__global__ __launch_bounds__(256) void embed_ln_k(
    const int* __restrict__ ids, const float* __restrict__ wemb,
    const float* __restrict__ pemb, const float* __restrict__ temb,
    const float* __restrict__ lns, const float* __restrict__ lnb,
    float* __restrict__ h32, f16* __restrict__ h16)
{
  const int row = blockIdx.x * 4 + (threadIdx.x >> 6);
  const int lane = threadIdx.x & 63;
  const int s = row & (S_ - 1);
  const float4* wp = (const float4*)(wemb + (size_t)ids[row] * H_);
  const float4* pp = (const float4*)(pemb + (size_t)s * H_);
  const float4* tp = (const float4*)temb;
  float4 x[3]; float sm = 0.f, sq = 0.f;
#pragma unroll
  for (int j = 0; j < 3; ++j) {
    int i4 = lane + 64 * j;
    float4 a = wp[i4], bb = pp[i4], c = tp[i4];
    float4 v; v.x = a.x + bb.x + c.x; v.y = a.y + bb.y + c.y;
    v.z = a.z + bb.z + c.z; v.w = a.w + bb.w + c.w;
    x[j] = v;
    sm += v.x + v.y + v.z + v.w;
    sq += v.x * v.x + v.y * v.y + v.z * v.z + v.w * v.w;
  }
#pragma unroll
  for (int o = 32; o > 0; o >>= 1) { sm += __shfl_xor(sm, o); sq += __shfl_xor(sq, o); }
  float mean = sm * (1.f / H_);
  float inv = rsqrtf(sq * (1.f / H_) - mean * mean + 1e-12f);
  float4* hw = (float4*)(h32 + (size_t)row * H_);
  f16* ho = h16 + (size_t)row * H_;
#pragma unroll
  for (int j = 0; j < 3; ++j) {
    int i4 = lane + 64 * j;
    float4 sc = ((const float4*)lns)[i4], bi = ((const float4*)lnb)[i4];
    float4 v = x[j], y;
    y.x = (v.x - mean) * inv * sc.x + bi.x;
    y.y = (v.y - mean) * inv * sc.y + bi.y;
    y.z = (v.z - mean) * inv * sc.z + bi.z;
    y.w = (v.w - mean) * inv * sc.w + bi.w;
    hw[i4] = y;
    f16x4 o4 = {(f16)y.x, (f16)y.y, (f16)y.z, (f16)y.w};
    *(f16x4*)&ho[i4 * 4] = o4;
  }
}

// compacted residual(h32 + tmpA f16 + tmpB f16) -> LN -> h32, h16
__global__ __launch_bounds__(256) void ln_res_k(
    float* __restrict__ h32, const f16* __restrict__ tmpA, const f16* __restrict__ tmpB,
    const float* __restrict__ lns, const float* __restrict__ lnb,
    f16* __restrict__ h16, const int* __restrict__ rowmap, const int* __restrict__ meta)
{
  const int crow = blockIdx.x * 4 + (threadIdx.x >> 6);
  if (crow >= meta[0]) return;
  const int row = rowmap[crow];
  const int lane = threadIdx.x & 63;
  const float4* hp = (const float4*)(h32 + (size_t)row * H_);
  const f16x4* ta = (const f16x4*)(tmpA + (size_t)row * H_);
  const f16x4* tb = (const f16x4*)(tmpB + (size_t)row * H_);
  float4 x[3]; float sm = 0.f, sq = 0.f;
#pragma unroll
  for (int j = 0; j < 3; ++j) {
    int i4 = lane + 64 * j;
    float4 a = hp[i4];
    f16x4 va = ta[i4], vb = tb[i4];
    float4 v;
    v.x = a.x + (float)va[0] + (float)vb[0];
    v.y = a.y + (float)va[1] + (float)vb[1];
    v.z = a.z + (float)va[2] + (float)vb[2];
    v.w = a.w + (float)va[3] + (float)vb[3];
    x[j] = v;
    sm += v.x + v.y + v.z + v.w;
    sq += v.x * v.x + v.y * v.y + v.z * v.z + v.w * v.w;
  }
#pragma unroll
  for (int o = 32; o > 0; o >>= 1) { sm += __shfl_xor(sm, o); sq += __shfl_xor(sq, o); }
  float mean = sm * (1.f / H_);
  float inv = rsqrtf(sq * (1.f / H_) - mean * mean + 1e-12f);
  float4* hw = (float4*)(h32 + (size_t)row * H_);
  f16* ho = h16 + (size_t)row * H_;
#pragma unroll
  for (int j = 0; j < 3; ++j) {
    int i4 = lane + 64 * j;
    float4 sc = ((const float4*)lns)[i4], bi = ((const float4*)lnb)[i4];
    float4 v = x[j], y;
    y.x = (v.x - mean) * inv * sc.x + bi.x;
    y.y = (v.y - mean) * inv * sc.y + bi.y;
    y.z = (v.z - mean) * inv * sc.z + bi.z;
    y.w = (v.w - mean) * inv * sc.w + bi.w;
    hw[i4] = y;
    f16x4 o4 = {(f16)y.x, (f16)y.y, (f16)y.z, (f16)y.w};
    *(f16x4*)&ho[i4 * 4] = o4;
  }
}

__global__ void len_k(const int* __restrict__ mask, int* __restrict__ len) {
  const int b = blockIdx.x;
  const int t = threadIdx.x;
  __shared__ int red[512];
  red[t] = mask[b * S_ + t]; __syncthreads();
  for (int o = 256; o > 0; o >>= 1) { if (t < o) red[t] += red[t + o]; __syncthreads(); }
  if (t == 0) len[b] = red[0];
}

// builds meta {Mv, Mpad} and compact->orig rowmap with dummy pad rows
__global__ void rowmap_k(const int* __restrict__ len, int* __restrict__ meta,
                         int* __restrict__ rowmap) {
  __shared__ int cum[17];
  if (threadIdx.x == 0) {
    int c = 0; cum[0] = 0;
    for (int b = 0; b < B_; ++b) { c += len[b]; cum[b + 1] = c; }
    meta[0] = c;
    meta[1] = (c + 127) & ~127;
  }
  __syncthreads();
  const int Mv = cum[16];
  for (int i = threadIdx.x; i < MTOK_ + MPADR_; i += 256) {
    int orig;
    if (i < Mv) {
      int b = 0;
#pragma unroll
      for (int t = 1; t <= 16; ++t) b += (i >= cum[t]) ? 1 : 0;
      orig = b * S_ + (i - cum[b]);
    } else {
      int d = i - Mv;
      orig = MTOK_ + (d < MPADR_ ? d : MPADR_ - 1);
    }
    rowmap[i] = orig;
  }
}

__global__ __launch_bounds__(256) void merge_k(
    const float* __restrict__ proj, const int* __restrict__ tl,
    float* __restrict__ means, float* __restrict__ masks)
{
  const int w = blockIdx.x, b = blockIdx.y;
  const int t = threadIdx.x;
  __shared__ int red[256];
  int part = 0;
  for (int j = t; j < w; j += 256) part += tl[b * W_ + j];
  red[t] = part; __syncthreads();
  for (int o = 128; o > 0; o >>= 1) { if (t < o) red[t] += red[t + o]; __syncthreads(); }
  const int start = red[0];
  const int len = tl[b * W_ + w];
  float s = 0.f;
  for (int l = 0; l < len; ++l)
    s += proj[((size_t)b * S_ + 1 + start + l) * WD_ + t];
  means[((size_t)b * W_ + w) * WD_ + t] = (len > 0) ? s / (float)len : 0.f;
  if (t == 0) masks[b * W_ + w] = (len > 0) ? 1.f : 0.f;
}

extern "C" void kernel_launch(void* const* d_in, const int* in_sizes, int n_in,
                              void* d_out, int out_size, void* d_ws, size_t ws_size,
                              hipStream_t stream)
{
  (void)in_sizes; (void)n_in; (void)out_size;
  const int*   ids   = (const int*)d_in[0];
  const int*   amask = (const int*)d_in[1];
  const int*   tlens = (const int*)d_in[2];
  const float* wemb  = (const float*)d_in[3];
  const float* pemb  = (const float*)d_in[4];
  const float* temb  = (const float*)d_in[5];
  const float* elns  = (const float*)d_in[6];
  const float* elnb  = (const float*)d_in[7];
  const float* Wq = (const float*)d_in[8];  const float* bq = (const float*)d_in[9];
  const float* Wk = (const float*)d_in[10]; const float* bk = (const float*)d_in[11];
  const float* Wv = (const float*)d_in[12]; const float* bv = (const float*)d_in[13];
  const float* Wo = (const float*)d_in[14]; const float* bo = (const float*)d_in[15];
  const float* l1s = (const float*)d_in[16]; const float* l1b = (const float*)d_in[17];
  const float* W1 = (const float*)d_in[18]; const float* b1 = (const float*)d_in[19];
  const float* W2 = (const float*)d_in[20]; const float* b2 = (const float*)d_in[21];
  const float* l2s = (const float*)d_in[22]; const float* l2b = (const float*)d_in[23];
  const float* pW = (const float*)d_in[24]; const float* pb = (const float*)d_in[25];

  const int MR = MTOK_ + MPADR_;   // rows incl. dummy pad region
  char* ws = (char*)d_ws;
  size_t off = 0;
  auto alloc = [&](size_t n) { void* r = ws + off; off += (n + 255) & ~(size_t)255; return r; };
  float* h32   = (float*)alloc((size_t)MR * H_ * 4);
  f16*   h16   = (f16*)alloc((size_t)MR * H_ * 2);
  f16*   qkv   = (f16*)alloc((size_t)MR * QKVN_ * 2);
  f16*   ctx16 = (f16*)alloc((size_t)MR * H_ * 2);
  f16*   vT    = (f16*)alloc((size_t)B_ * NH_ * DH_ * S_ * 2);
  f16*   ff16  = (f16*)alloc((size_t)MR * FF_ * 2);
  f16*   tmp16 = (f16*)alloc((size_t)MR * H_ * 2 * 2);   // 2 split-K halves
  float* proj32 = (float*)alloc((size_t)MR * WD_ * 4);
  f16*   pwT   = (f16*)alloc((size_t)WD_ * H_ * 2);
  float* bqkv  = (float*)alloc((size_t)L_ * QKVN_ * 4);
  int*   lenb  = (int*)alloc(256);
  int*   meta  = (int*)alloc(256);
  int*   rowmap = (int*)alloc((size_t)MR * 4);
  f16*   tmp16b = tmp16 + (size_t)MR * H_;

  const size_t wqkv_sz = (size_t)QKVN_ * H_ * 2;
  const size_t wo_sz   = (size_t)H_ * H_ * 2;
  const size_t w1_sz   = (size_t)H_ * FF_ * 2;
  const size_t w2_sz   = (size_t)FF_ * H_ * 2;
  const size_t per_layer_w = wqkv_sz + wo_sz + w1_sz + w2_sz;
  const bool big = ws_size >= off + (size_t)L_ * per_layer_w + 8192;
  const int nz = big ? L_ : 1;
  f16* wqkv0 = (f16*)alloc((size_t)nz * wqkv_sz);
  f16* wo0   = (f16*)alloc((size_t)nz * wo_sz);
  f16* w10   = (f16*)alloc((size_t)nz * w1_sz);
  f16* w20   = (f16*)alloc((size_t)nz * w2_sz);

  len_k<<<B_, 512, 0, stream>>>(amask, lenb);
  rowmap_k<<<1, 256, 0, stream>>>(lenb, meta, rowmap);
  embed_ln_k<<<MTOK_ / 4, 256, 0, stream>>>(ids, wemb, pemb, temb, elns, elnb, h32, h16);
  transpose_f16_k<float><<<dim3(WD_/32, H_/32, 1), 256, 0, stream>>>(pW, pwT, WD_, H_, 0, 0);
  bias_cat_k<<<dim3(QKVN_/256, L_), 256, 0, stream>>>(bq, bk, bv, bqkv);

  if (big) {
    transpose_f16_k<float><<<dim3(H_/32, H_/32, L_), 256, 0, stream>>>(
        Wq, wqkv0,                   H_, H_, (long)H_*H_, (long)QKVN_*H_);
    transpose_f16_k<float><<<dim3(H_/32, H_/32, L_), 256, 0, stream>>>(
        Wk, wqkv0 + (size_t)H_*H_,   H_, H_, (long)H_*H_, (long)QKVN_*H_);
    transpose_f16_k<float><<<dim3(H_/32, H_/32, L_), 256, 0, stream>>>(
        Wv, wqkv0 + (size_t)2*H_*H_, H_, H_, (long)H_*H_, (long)QKVN_*H_);
    transpose_f16_k<float><<<dim3(H_/32, H_/32, L_), 256, 0, stream>>>(
        Wo, wo0, H_, H_, (long)H_*H_, (long)H_*H_);
    transpose_f16_k<float><<<dim3(FF_/32, H_/32, L_), 256, 0, stream>>>(
        W1, w10, FF_, H_, (long)H_*FF_, (long)H_*FF_);
    transpose_f16_k<float><<<dim3(H_/32, FF_/32, L_), 256, 0, stream>>>(
        W2, w20, H_, FF_, (long)FF_*H_, (long)FF_*H_);
  }

  for (int l = 0; l < L_; ++l) {
    f16* wqkv_l = wqkv0 + (size_t)(big ? l : 0) * QKVN_ * H_;
    f16* wo_l   = wo0   + (size_t)(big ? l : 0) * H_ * H_;
    f16* w1_l   = w10   + (size_t)(big ? l : 0) * H_ * FF_;
    f16* w2_l   = w20   + (size_t)(big ? l : 0) * FF_ * H_;
    if (!big) {
      transpose_f16_k<float><<<dim3(H_/32, H_/32, 1), 256, 0, stream>>>(
          Wq + (size_t)l*H_*H_, wqkv_l,                   H_, H_, 0, 0);
      transpose_f16_k<float><<<dim3(H_/32, H_/32, 1), 256, 0, stream>>>(
          Wk + (size_t)l*H_*H_, wqkv_l + (size_t)H_*H_,   H_, H_, 0, 0);
      transpose_f16_k<float><<<dim3(H_/32, H_/32, 1), 256, 0, stream>>>(
          Wv + (size_t)l*H_*H_, wqkv_l + (size_t)2*H_*H_, H_, H_, 0, 0);
      transpose_f16_k<float><<<dim3(H_/32, H_/32, 1), 256, 0, stream>>>(
          Wo + (size_t)l*H_*H_, wo_l, H_, H_, 0, 0);
      transpose_f16_k<float><<<dim3(FF_/32, H_/32, 1), 256, 0, stream>>>(
          W1 + (size_t)l*H_*FF_, w1_l, FF_, H_, 0, 0);
      transpose_f16_k<float><<<dim3(H_/32, FF_/32, 1), 256, 0, stream>>>(
          W2 + (size_t)l*FF_*H_, w2_l, H_, FF_, 0, 0);
    }
    // fused QKV projection (128x128, 64x64 wave tiles); V cols -> vT transposed
    gemm2_k<128,128,0,1,1,1,1><<<dim3(QKVN_/128, MTOK_/128, 1), 256, 0, stream>>>(
        h16, wqkv_l, qkv, bqkv + (size_t)l*QKVN_, vT, rowmap, meta, H_, H_, QKVN_, H_, 1.0f, 0);
    // fused flash attention -> ctx16
    fattn_k<<<dim3(B_*NH_, S_/128), 256, 0, stream>>>(qkv, vT, ctx16, lenb);
    // O projection, split-K=2 -> tmp16/tmp16b, then LN(residual, sum of halves)
    gemm2_k<64,128,0,1,1,0,2><<<dim3(H_/128, MTOK_/64, 2), 256, 0, stream>>>(
        ctx16, wo_l, tmp16, bo + (size_t)l*H_, nullptr, rowmap, meta, H_, H_, H_, H_, 1.0f, (long)MR * H_);
    ln_res_k<<<MTOK_/4, 256, 0, stream>>>(h32, tmp16, tmp16b, l1s + (size_t)l*H_, l1b + (size_t)l*H_, h16, rowmap, meta);
    // FFN: FF1 128x128 (64x64 wave tiles), FF2 split-K=2
    gemm2_k<128,128,1,1,1,0,1><<<dim3(FF_/128, MTOK_/128, 1), 256, 0, stream>>>(
        h16, w1_l, ff16, b1 + (size_t)l*FF_, nullptr, rowmap, meta, H_, H_, FF_, H_, 1.0f, 0);
    gemm2_k<64,128,0,1,1,0,2><<<dim3(H_/128, MTOK_/64, 2), 256, 0, stream>>>(
        ff16, w2_l, tmp16, b2 + (size_t)l*H_, nullptr, rowmap, meta, FF_, FF_, H_, FF_, 1.0f, (long)MR * H_);
    ln_res_k<<<MTOK_/4, 256, 0, stream>>>(h32, tmp16, tmp16b, l2s + (size_t)l*H_, l2b + (size_t)l*H_, h16, rowmap, meta);
  }

  // projection to word dims (compacted M)
  gemm2_k<64,64,0,0,1,0,1><<<dim3(WD_/64, MTOK_/64, 1), 256, 0, stream>>>(
      h16, pwT, proj32, pb, nullptr, rowmap, meta, H_, H_, WD_, H_, 1.0f, 0);
  merge_k<<<dim3(W_, B_), 256, 0, stream>>>(proj32, tlens,
      (float*)d_out, (float*)d_out + (size_t)B_ * W_ * WD_);
}

// Round 11
// 2344.136 us; speedup vs baseline: 1.0563x; 1.0563x over previous
//
#include <hip/hip_runtime.h>
#include <stdint.h>

#define B_ 16
#define S_ 512
#define H_ 768
#define L_ 12
#define NH_ 12
#define DH_ 64
#define FF_ 3072
#define WD_ 256
#define W_ 255
#define MTOK_ (B_*S_)
#define QKVN_ 2304
#define MPADR_ 128   // dummy pad rows appended to row-indexed buffers

typedef _Float16 f16;
typedef _Float16 f16x8 __attribute__((ext_vector_type(8)));
typedef _Float16 f16x4 __attribute__((ext_vector_type(4)));
typedef _Float16 f16x2 __attribute__((ext_vector_type(2)));
typedef float f32x4 __attribute__((ext_vector_type(4)));

#define SCHED_FENCE() __builtin_amdgcn_sched_barrier(0)

// tanh-form gelu via exp-sigmoid; max |dev| vs exact ~7e-4 (threshold margin 3x)
__device__ __forceinline__ float gelu_fast(float x) {
  float u = x * (1.0f + 0.044715f * x * x);
  float e = __expf(-1.5957691216f * u);
  return __fdividef(x, 1.0f + e);
}

__device__ __forceinline__ void gload16(const f16* g, f16* l) {
  __builtin_amdgcn_global_load_lds(
      (const __attribute__((address_space(1))) void*)g,
      (__attribute__((address_space(3))) void*)l, 16, 0, 0);
}

// Row-compacted GEMM, SINGLE-buffered m97 structure (32KB @128x128 -> 3
// blocks/CU; 16KB @64x64 -> 8 blocks/CU). Implicit cross-block wave overlap
// hides the barrier drain (m114); explicit dbuf never beat this (m99/m100).
// Early exit on ORIGINAL flat id (dead tail XCD-balanced), bijective XCD
// swizzle within live count. QKVW=1: cols >= 2*H_ -> vT[bh][d][s].
template<int BM, int BN, int ACT, int OUTF16, int BIAS, int QKVW>
__global__ __launch_bounds__(256) void gemm2_k(
    const f16* __restrict__ A, const f16* __restrict__ Bm, void* __restrict__ Cv,
    const float* __restrict__ bias, f16* __restrict__ vTp,
    const int* __restrict__ rowmap, const int* __restrict__ meta,
    int lda, int ldb, int ldc, int K, float scale)
{
  constexpr int MI = BM / 32;
  constexpr int NI = BN / 32;
  const int gx = gridDim.x;
  int flat = blockIdx.y * gx + blockIdx.x;
  const int nlive = (meta[1] / BM) * gx;
  if (flat >= nlive) return;                // uniform: whole block exits pre-barrier
  {
    int q = nlive >> 3, r = nlive & 7;
    int xcd = flat & 7, idx = flat >> 3;
    flat = (xcd < r ? xcd * (q + 1) : r * (q + 1) + (xcd - r) * q) + idx;
  }
  const int row0 = (flat / gx) * BM;
  const int col0 = (flat % gx) * BN;

  __shared__ __align__(16) f16 lA[BM * 64];
  __shared__ __align__(16) f16 lB[BN * 64];
  const int lane = threadIdx.x & 63;
  const int wave = threadIdx.x >> 6;
  const int wr = wave >> 1, wc = wave & 1;
  const int srow = lane >> 3;
  const int scol = lane & 7;
  const int cs = scol ^ srow;

  int arow[BM / 32];
#pragma unroll
  for (int i = 0; i < BM / 32; ++i)
    arow[i] = rowmap[row0 + (wave * (BM / 32) + i) * 8 + srow];

  f32x4 acc[MI][NI] = {};
  const int nt = K >> 6;
  const int rl = lane & 15, g = lane >> 4;
  for (int t = 0; t < nt; ++t) {
    __syncthreads();                        // all waves done reading previous tile
    const int k0 = t * 64;
#pragma unroll
    for (int i = 0; i < BM / 32; ++i) {
      int seg = wave * (BM / 32) + i;
      gload16(&A[(size_t)arow[i] * lda + k0 + cs * 8], &lA[seg * 512]);
    }
#pragma unroll
    for (int i = 0; i < BN / 32; ++i) {
      int seg = wave * (BN / 32) + i;
      gload16(&Bm[(size_t)(col0 + seg * 8 + srow) * ldb + k0 + cs * 8], &lB[seg * 512]);
    }
    __syncthreads();                        // drains vmcnt(0): tile landed
#pragma unroll
    for (int c = 0; c < 2; ++c) {
      f16x8 af[MI], bf[NI];
#pragma unroll
      for (int mi = 0; mi < MI; ++mi) {
        int r = wr * (MI * 16) + mi * 16 + rl;
        int u = (c * 4 + g) ^ (r & 7);
        af[mi] = *(const f16x8*)&lA[r * 64 + u * 8];
      }
#pragma unroll
      for (int ni = 0; ni < NI; ++ni) {
        int r = wc * (NI * 16) + ni * 16 + rl;
        int u = (c * 4 + g) ^ (r & 7);
        bf[ni] = *(const f16x8*)&lB[r * 64 + u * 8];
      }
#pragma unroll
      for (int mi = 0; mi < MI; ++mi)
#pragma unroll
        for (int ni = 0; ni < NI; ++ni)
          acc[mi][ni] = __builtin_amdgcn_mfma_f32_16x16x32_f16(af[mi], bf[ni], acc[mi][ni], 0, 0, 0);
    }
  }
  // epilogue: C/D layout col=lane&15, row=(lane>>4)*4+reg; rows via rowmap
  const int cl = lane & 15;
  const int rq = (lane >> 4) * 4;
#pragma unroll
  for (int mi = 0; mi < MI; ++mi) {
    const int4 rm4 = *(const int4*)&rowmap[row0 + wr * (MI * 16) + mi * 16 + rq];
    const int rows[4] = { rm4.x, rm4.y, rm4.z, rm4.w };
    const bool contig = (rm4.w == rm4.x + 3) && ((rm4.x & 3) == 0);
#pragma unroll
    for (int ni = 0; ni < NI; ++ni) {
      int col = col0 + wc * (NI * 16) + ni * 16 + cl;
      float bv = 0.f;
      if constexpr (BIAS) bv = bias[col];
      if constexpr (QKVW) {
        if (col >= 2 * H_) {                 // transposed V write: vT[bh][d][s]
          int vc = col - 2 * H_;
          int h = vc >> 6, d = vc & 63;
          if (contig) {
            if (rm4.x < MTOK_) {
              int b = rm4.x >> 9, s = rm4.x & (S_ - 1);
              f16x4 o4;
#pragma unroll
              for (int r = 0; r < 4; ++r) o4[r] = (f16)(acc[mi][ni][r] * scale + bv);
              *(f16x4*)&vTp[(((size_t)(b * NH_ + h)) * DH_ + d) * S_ + s] = o4;
            }
          } else {
#pragma unroll
            for (int r = 0; r < 4; ++r) {
              int orow = rows[r];
              if (orow < MTOK_) {
                int b = orow >> 9, s = orow & (S_ - 1);
                vTp[(((size_t)(b * NH_ + h)) * DH_ + d) * S_ + s] = (f16)(acc[mi][ni][r] * scale + bv);
              }
            }
          }
          continue;
        }
      }
#pragma unroll
      for (int r = 0; r < 4; ++r) {
        float v = acc[mi][ni][r] * scale + bv;
        if constexpr (ACT == 1) v = gelu_fast(v);
        if constexpr (OUTF16) {
          ((f16*)Cv)[(size_t)rows[r] * ldc + col] = (f16)v;
        } else {
          ((float*)Cv)[(size_t)rows[r] * ldc + col] = v;
        }
      }
    }
  }
}

// Fused flash attention with issue-early staging + counted vmcnt (1-ahead).
// grid (b*NH, qtile): dead q-tiles form the dispatch tail -> XCD-balanced.
// Swapped QK^T -> S^T acc. No-max softmax (scores O(1), shift-invariant;
// masked kv -> exact 0).
__global__ __launch_bounds__(256) void fattn_k(
    const f16* __restrict__ qkv, const f16* __restrict__ vT,
    f16* __restrict__ ctx, const int* __restrict__ lenp)
{
  const int bh = blockIdx.x, qt = blockIdx.y;
  const int b = bh / NH_, h = bh - b * NH_;
  const int L = lenp[b];
  if ((qt << 7) >= L) return;               // uniform per block
  const int nkt = (L + 63) >> 6;
  const int lane = threadIdx.x & 63, wave = threadIdx.x >> 6;
  const int rl = lane & 15, g = lane >> 4;
  const int srow = lane >> 3, scol = lane & 7;
  const int cs = scol ^ srow;

  __shared__ __align__(16) f16 lK[2][64 * 64];
  __shared__ __align__(16) f16 lV[2][64 * 64];
  __shared__ __align__(16) f16 lP[128 * 72];

  auto stage = [&](int p, int kt) {       // 4 gload16 per wave
#pragma unroll
    for (int i = 0; i < 2; ++i) {
      int seg = wave * 2 + i;
      int r = seg * 8 + srow;
      gload16(&qkv[((size_t)b * S_ + kt * 64 + r) * QKVN_ + H_ + h * DH_ + cs * 8], &lK[p][seg * 512]);
      gload16(&vT[((size_t)bh * DH_ + r) * S_ + kt * 64 + cs * 8], &lV[p][seg * 512]);
    }
  };

  const size_t qrow0 = (size_t)b * S_ + qt * 128 + wave * 32;
  f16x8 qf[2][2];
#pragma unroll
  for (int bq = 0; bq < 2; ++bq)
#pragma unroll
    for (int kc = 0; kc < 2; ++kc)
      qf[bq][kc] = *(const f16x8*)&qkv[(qrow0 + bq * 16 + rl) * QKVN_ + h * DH_ + kc * 32 + g * 8];

  float lsum[2] = {0.f, 0.f};
  f32x4 accO[2][4] = {};

  stage(0, 0);
  for (int kt = 0; kt < nkt; ++kt) {
    // issue next stage BEFORE waiting; buf^1 reads finished at prev B2
    if (kt + 1 < nkt) {
      stage((kt + 1) & 1, kt + 1);
      asm volatile("s_waitcnt vmcnt(4) lgkmcnt(0)" ::: "memory");
    } else {
      asm volatile("s_waitcnt vmcnt(0) lgkmcnt(0)" ::: "memory");
    }
    SCHED_FENCE();
    __builtin_amdgcn_s_barrier();           // B1: all stage(kt) complete
    SCHED_FENCE();
    const int p = kt & 1;

    f32x4 accS[4][2] = {};
    __builtin_amdgcn_s_setprio(1);
#pragma unroll
    for (int kc = 0; kc < 2; ++kc) {
#pragma unroll
      for (int ak = 0; ak < 4; ++ak) {
        int row = ak * 16 + rl;
        int u = (kc * 4 + g) ^ (row & 7);
        f16x8 kf = *(const f16x8*)&lK[p][row * 64 + u * 8];
#pragma unroll
        for (int bq = 0; bq < 2; ++bq)
          accS[ak][bq] = __builtin_amdgcn_mfma_f32_16x16x32_f16(kf, qf[bq][kc], accS[ak][bq], 0, 0, 0);
      }
    }
    __builtin_amdgcn_s_setprio(0);

    const int kvb = kt * 64 + g * 4;
#pragma unroll
    for (int bq = 0; bq < 2; ++bq) {
      float pv[16];
      float ps = 0.f;
#pragma unroll
      for (int ak = 0; ak < 4; ++ak)
#pragma unroll
        for (int r = 0; r < 4; ++r) {
          float s = accS[ak][bq][r] * 0.125f;
          float pp = (kvb + ak * 16 + r < L) ? __expf(s) : 0.f;
          pv[ak * 4 + r] = pp;
          ps += pp;
        }
      ps += __shfl_xor(ps, 16);
      ps += __shfl_xor(ps, 32);
      lsum[bq] += ps;
      const int qrow = wave * 32 + bq * 16 + rl;
#pragma unroll
      for (int ak = 0; ak < 4; ++ak)
#pragma unroll
        for (int r2 = 0; r2 < 2; ++r2) {
          f16x2 pk = { (f16)pv[ak * 4 + r2 * 2], (f16)pv[ak * 4 + r2 * 2 + 1] };
          *(f16x2*)&lP[qrow * 72 + ak * 16 + g * 4 + r2 * 2] = pk;
        }
    }
    __builtin_amdgcn_s_setprio(1);
#pragma unroll
    for (int kc = 0; kc < 2; ++kc) {
      f16x8 pa[2], vf[4];
#pragma unroll
      for (int aq = 0; aq < 2; ++aq) {
        int prow = wave * 32 + aq * 16 + rl;
        pa[aq] = *(const f16x8*)&lP[prow * 72 + kc * 32 + g * 8];
      }
#pragma unroll
      for (int bd = 0; bd < 4; ++bd) {
        int vrow = bd * 16 + rl;
        int u = (kc * 4 + g) ^ (vrow & 7);
        vf[bd] = *(const f16x8*)&lV[p][vrow * 64 + u * 8];
      }
#pragma unroll
      for (int aq = 0; aq < 2; ++aq)
#pragma unroll
        for (int bd = 0; bd < 4; ++bd)
          accO[aq][bd] = __builtin_amdgcn_mfma_f32_16x16x32_f16(pa[aq], vf[bd], accO[aq][bd], 0, 0, 0);
    }
    __builtin_amdgcn_s_setprio(0);
    SCHED_FENCE();
    asm volatile("s_waitcnt lgkmcnt(0)" ::: "memory");
    SCHED_FENCE();
    __builtin_amdgcn_s_barrier();           // B2: all reads of buf[kt&1] done
    SCHED_FENCE();
  }

  float linv[2] = { 1.f / lsum[0], 1.f / lsum[1] };
  const size_t orow0 = (size_t)b * S_ + qt * 128 + wave * 32;
#pragma unroll
  for (int aq = 0; aq < 2; ++aq)
#pragma unroll
    for (int r = 0; r < 4; ++r) {
      float li = __shfl(linv[aq], (lane & 48) | (g * 4 + r));
      int q = aq * 16 + g * 4 + r;
#pragma unroll
      for (int bd = 0; bd < 4; ++bd)
        ctx[(orow0 + q) * H_ + h * DH_ + bd * 16 + rl] = (f16)(accO[aq][bd][r] * li);
    }
}

// out[n*ldout + k] = (f16) in[k*ldin + n]; 32x32 tiles, batched via z.
template<typename TI>
__global__ __launch_bounds__(256) void transpose_f16_k(
    const TI* __restrict__ in, f16* __restrict__ out,
    int ldin, int ldout, long i1, long o1)
{
  const int z = blockIdx.z;
  in  += (size_t)z * i1;
  out += (size_t)z * o1;
  __shared__ float t[32][33];
  const int kt = blockIdx.y * 32, nt = blockIdx.x * 32;
  const int tx = threadIdx.x & 31, tg = threadIdx.x >> 5;
#pragma unroll
  for (int i = 0; i < 4; ++i) {
    int k = tg * 4 + i;
    t[k][tx] = (float)in[(size_t)(kt + k) * ldin + nt + tx];
  }
  __syncthreads();
#pragma unroll
  for (int i = 0; i < 4; ++i) {
    int n = tg * 4 + i;
    out[(size_t)(nt + n) * ldout + kt + tx] = (f16)t[tx][n];
  }
}

__global__ void bias_cat_k(const float* __restrict__ bq, const float* __restrict__ bk,
                           const float* __restrict__ bv, float* __restrict__ out) {
  const int l = blockIdx.y;
  const int j = blockIdx.x * 256 + threadIdx.x;
  float v = (j < H_) ? bq[l * H_ + j] : (j < 2 * H_) ? bk[l * H_ + j - H_] : bv[l * H_ + j - 2 * H_];
  out[l * QKVN_ + j] = v;
}

__global__ __launch_bounds__(256) void embed_ln_k(
    const int* __restrict__ ids, const float* __restrict__ wemb,
    const float* __restrict__ pemb, const float* __restrict__ temb,
    const float* __restrict__ lns, const float* __restrict__ lnb,
    float* __restrict__ h32, f16* __restrict__ h16)
{
  const int row = blockIdx.x * 4 + (threadIdx.x >> 6);
  const int lane = threadIdx.x & 63;
  const int s = row & (S_ - 1);
  const float4* wp = (const float4*)(wemb + (size_t)ids[row] * H_);
  const float4* pp = (const float4*)(pemb + (size_t)s * H_);
  const float4* tp = (const float4*)temb;
  float4 x[3]; float sm = 0.f, sq = 0.f;
#pragma unroll
  for (int j = 0; j < 3; ++j) {
    int i4 = lane + 64 * j;
    float4 a = wp[i4], bb = pp[i4], c = tp[i4];
    float4 v; v.x = a.x + bb.x + c.x; v.y = a.y + bb.y + c.y;
    v.z = a.z + bb.z + c.z; v.w = a.w + bb.w + c.w;
    x[j] = v;
    sm += v.x + v.y + v.z + v.w;
    sq += v.x * v.x + v.y * v.y + v.z * v.z + v.w * v.w;
  }
#pragma unroll
  for (int o = 32; o > 0; o >>= 1) { sm += __shfl_xor(sm, o); sq += __shfl_xor(sq, o); }
  float mean = sm * (1.f / H_);
  float inv = rsqrtf(sq * (1.f / H_) - mean * mean + 1e-12f);
  float4* hw = (float4*)(h32 + (size_t)row * H_);
  f16* ho = h16 + (size_t)row * H_;
#pragma unroll
  for (int j = 0; j < 3; ++j) {
    int i4 = lane + 64 * j;
    float4 sc = ((const float4*)lns)[i4], bi = ((const float4*)lnb)[i4];
    float4 v = x[j], y;
    y.x = (v.x - mean) * inv * sc.x + bi.x;
    y.y = (v.y - mean) * inv * sc.y + bi.y;
    y.z = (v.z - mean) * inv * sc.z + bi.z;
    y.w = (v.w - mean) * inv * sc.w + bi.w;
    hw[i4] = y;
    f16x4 o4 = {(f16)y.x, (f16)y.y, (f16)y.z, (f16)y.w};
    *(f16x4*)&ho[i4 * 4] = o4;
  }
}

// compacted residual(h32 + tmp f16) -> LN -> h32, h16 (rows via rowmap)
__global__ __launch_bounds__(256) void ln_res_k(
    float* __restrict__ h32, const f16* __restrict__ tmp,
    const float* __restrict__ lns, const float* __restrict__ lnb,
    f16* __restrict__ h16, const int* __restrict__ rowmap, const int* __restrict__ meta)
{
  const int crow = blockIdx.x * 4 + (threadIdx.x >> 6);
  if (crow >= meta[0]) return;
  const int row = rowmap[crow];
  const int lane = threadIdx.x & 63;
  const float4* hp = (const float4*)(h32 + (size_t)row * H_);
  const f16x4* tp = (const f16x4*)(tmp + (size_t)row * H_);
  float4 x[3]; float sm = 0.f, sq = 0.f;
#pragma unroll
  for (int j = 0; j < 3; ++j) {
    int i4 = lane + 64 * j;
    float4 a = hp[i4];
    f16x4 tv = tp[i4];
    float4 v; v.x = a.x + (float)tv[0]; v.y = a.y + (float)tv[1];
    v.z = a.z + (float)tv[2]; v.w = a.w + (float)tv[3];
    x[j] = v;
    sm += v.x + v.y + v.z + v.w;
    sq += v.x * v.x + v.y * v.y + v.z * v.z + v.w * v.w;
  }
#pragma unroll
  for (int o = 32; o > 0; o >>= 1) { sm += __shfl_xor(sm, o); sq += __shfl_xor(sq, o); }
  float mean = sm * (1.f / H_);
  float inv = rsqrtf(sq * (1.f / H_) - mean * mean + 1e-12f);
  float4* hw = (float4*)(h32 + (size_t)row * H_);
  f16* ho = h16 + (size_t)row * H_;
#pragma unroll
  for (int j = 0; j < 3; ++j) {
    int i4 = lane + 64 * j;
    float4 sc = ((const float4*)lns)[i4], bi = ((const float4*)lnb)[i4];
    float4 v = x[j], y;
    y.x = (v.x - mean) * inv * sc.x + bi.x;
    y.y = (v.y - mean) * inv * sc.y + bi.y;
    y.z = (v.z - mean) * inv * sc.z + bi.z;
    y.w = (v.w - mean) * inv * sc.w + bi.w;
    hw[i4] = y;
    f16x4 o4 = {(f16)y.x, (f16)y.y, (f16)y.z, (f16)y.w};
    *(f16x4*)&ho[i4 * 4] = o4;
  }
}

__global__ void len_k(const int* __restrict__ mask, int* __restrict__ len) {
  const int b = blockIdx.x;
  const int t = threadIdx.x;
  __shared__ int red[512];
  red[t] = mask[b * S_ + t]; __syncthreads();
  for (int o = 256; o > 0; o >>= 1) { if (t < o) red[t] += red[t + o]; __syncthreads(); }
  if (t == 0) len[b] = red[0];
}

// builds meta {Mv, Mpad} and compact->orig rowmap with dummy pad rows
__global__ void rowmap_k(const int* __restrict__ len, int* __restrict__ meta,
                         int* __restrict__ rowmap) {
  __shared__ int cum[17];
  if (threadIdx.x == 0) {
    int c = 0; cum[0] = 0;
    for (int b = 0; b < B_; ++b) { c += len[b]; cum[b + 1] = c; }
    meta[0] = c;
    meta[1] = (c + 127) & ~127;
  }
  __syncthreads();
  const int Mv = cum[16];
  for (int i = threadIdx.x; i < MTOK_ + MPADR_; i += 256) {
    int orig;
    if (i < Mv) {
      int b = 0;
#pragma unroll
      for (int t = 1; t <= 16; ++t) b += (i >= cum[t]) ? 1 : 0;
      orig = b * S_ + (i - cum[b]);
    } else {
      int d = i - Mv;
      orig = MTOK_ + (d < MPADR_ ? d : MPADR_ - 1);
    }
    rowmap[i] = orig;
  }
}

__global__ __launch_bounds__(256) void merge_k(
    const float* __restrict__ proj, const int* __restrict__ tl,
    float* __restrict__ means, float* __restrict__ masks)
{
  const int w = blockIdx.x, b = blockIdx.y;
  const int t = threadIdx.x;
  __shared__ int red[256];
  int part = 0;
  for (int j = t; j < w; j += 256) part += tl[b * W_ + j];
  red[t] = part; __syncthreads();
  for (int o = 128; o > 0; o >>= 1) { if (t < o) red[t] += red[t + o]; __syncthreads(); }
  const int start = red[0];
  const int len = tl[b * W_ + w];
  float s = 0.f;
  for (int l = 0; l < len; ++l)
    s += proj[((size_t)b * S_ + 1 + start + l) * WD_ + t];
  means[((size_t)b * W_ + w) * WD_ + t] = (len > 0) ? s / (float)len : 0.f;
  if (t == 0) masks[b * W_ + w] = (len > 0) ? 1.f : 0.f;
}

extern "C" void kernel_launch(void* const* d_in, const int* in_sizes, int n_in,
                              void* d_out, int out_size, void* d_ws, size_t ws_size,
                              hipStream_t stream)
{
  (void)in_sizes; (void)n_in; (void)out_size;
  const int*   ids   = (const int*)d_in[0];
  const int*   amask = (const int*)d_in[1];
  const int*   tlens = (const int*)d_in[2];
  const float* wemb  = (const float*)d_in[3];
  const float* pemb  = (const float*)d_in[4];
  const float* temb  = (const float*)d_in[5];
  const float* elns  = (const float*)d_in[6];
  const float* elnb  = (const float*)d_in[7];
  const float* Wq = (const float*)d_in[8];  const float* bq = (const float*)d_in[9];
  const float* Wk = (const float*)d_in[10]; const float* bk = (const float*)d_in[11];
  const float* Wv = (const float*)d_in[12]; const float* bv = (const float*)d_in[13];
  const float* Wo = (const float*)d_in[14]; const float* bo = (const float*)d_in[15];
  const float* l1s = (const float*)d_in[16]; const float* l1b = (const float*)d_in[17];
  const float* W1 = (const float*)d_in[18]; const float* b1 = (const float*)d_in[19];
  const float* W2 = (const float*)d_in[20]; const float* b2 = (const float*)d_in[21];
  const float* l2s = (const float*)d_in[22]; const float* l2b = (const float*)d_in[23];
  const float* pW = (const float*)d_in[24]; const float* pb = (const float*)d_in[25];

  const int MR = MTOK_ + MPADR_;   // rows incl. dummy pad region
  char* ws = (char*)d_ws;
  size_t off = 0;
  auto alloc = [&](size_t n) { void* r = ws + off; off += (n + 255) & ~(size_t)255; return r; };
  float* h32   = (float*)alloc((size_t)MR * H_ * 4);
  f16*   h16   = (f16*)alloc((size_t)MR * H_ * 2);
  f16*   qkv   = (f16*)alloc((size_t)MR * QKVN_ * 2);
  f16*   ctx16 = (f16*)alloc((size_t)MR * H_ * 2);
  f16*   vT    = (f16*)alloc((size_t)B_ * NH_ * DH_ * S_ * 2);
  f16*   ff16  = (f16*)alloc((size_t)MR * FF_ * 2);
  f16*   tmp16 = (f16*)alloc((size_t)MR * H_ * 2);
  float* proj32 = (float*)alloc((size_t)MR * WD_ * 4);
  f16*   pwT   = (f16*)alloc((size_t)WD_ * H_ * 2);
  float* bqkv  = (float*)alloc((size_t)L_ * QKVN_ * 4);
  int*   lenb  = (int*)alloc(256);
  int*   meta  = (int*)alloc(256);
  int*   rowmap = (int*)alloc((size_t)MR * 4);

  const size_t wqkv_sz = (size_t)QKVN_ * H_ * 2;
  const size_t wo_sz   = (size_t)H_ * H_ * 2;
  const size_t w1_sz   = (size_t)H_ * FF_ * 2;
  const size_t w2_sz   = (size_t)FF_ * H_ * 2;
  const size_t per_layer_w = wqkv_sz + wo_sz + w1_sz + w2_sz;
  const bool big = ws_size >= off + (size_t)L_ * per_layer_w + 8192;
  const int nz = big ? L_ : 1;
  f16* wqkv0 = (f16*)alloc((size_t)nz * wqkv_sz);
  f16* wo0   = (f16*)alloc((size_t)nz * wo_sz);
  f16* w10   = (f16*)alloc((size_t)nz * w1_sz);
  f16* w20   = (f16*)alloc((size_t)nz * w2_sz);

  len_k<<<B_, 512, 0, stream>>>(amask, lenb);
  rowmap_k<<<1, 256, 0, stream>>>(lenb, meta, rowmap);
  embed_ln_k<<<MTOK_ / 4, 256, 0, stream>>>(ids, wemb, pemb, temb, elns, elnb, h32, h16);
  transpose_f16_k<float><<<dim3(WD_/32, H_/32, 1), 256, 0, stream>>>(pW, pwT, WD_, H_, 0, 0);
  bias_cat_k<<<dim3(QKVN_/256, L_), 256, 0, stream>>>(bq, bk, bv, bqkv);

  if (big) {
    transpose_f16_k<float><<<dim3(H_/32, H_/32, L_), 256, 0, stream>>>(
        Wq, wqkv0,                   H_, H_, (long)H_*H_, (long)QKVN_*H_);
    transpose_f16_k<float><<<dim3(H_/32, H_/32, L_), 256, 0, stream>>>(
        Wk, wqkv0 + (size_t)H_*H_,   H_, H_, (long)H_*H_, (long)QKVN_*H_);
    transpose_f16_k<float><<<dim3(H_/32, H_/32, L_), 256, 0, stream>>>(
        Wv, wqkv0 + (size_t)2*H_*H_, H_, H_, (long)H_*H_, (long)QKVN_*H_);
    transpose_f16_k<float><<<dim3(H_/32, H_/32, L_), 256, 0, stream>>>(
        Wo, wo0, H_, H_, (long)H_*H_, (long)H_*H_);
    transpose_f16_k<float><<<dim3(FF_/32, H_/32, L_), 256, 0, stream>>>(
        W1, w10, FF_, H_, (long)H_*FF_, (long)H_*FF_);
    transpose_f16_k<float><<<dim3(H_/32, FF_/32, L_), 256, 0, stream>>>(
        W2, w20, H_, FF_, (long)FF_*H_, (long)FF_*H_);
  }

  for (int l = 0; l < L_; ++l) {
    f16* wqkv_l = wqkv0 + (size_t)(big ? l : 0) * QKVN_ * H_;
    f16* wo_l   = wo0   + (size_t)(big ? l : 0) * H_ * H_;
    f16* w1_l   = w10   + (size_t)(big ? l : 0) * H_ * FF_;
    f16* w2_l   = w20   + (size_t)(big ? l : 0) * FF_ * H_;
    if (!big) {
      transpose_f16_k<float><<<dim3(H_/32, H_/32, 1), 256, 0, stream>>>(
          Wq + (size_t)l*H_*H_, wqkv_l,                   H_, H_, 0, 0);
      transpose_f16_k<float><<<dim3(H_/32, H_/32, 1), 256, 0, stream>>>(
          Wk + (size_t)l*H_*H_, wqkv_l + (size_t)H_*H_,   H_, H_, 0, 0);
      transpose_f16_k<float><<<dim3(H_/32, H_/32, 1), 256, 0, stream>>>(
          Wv + (size_t)l*H_*H_, wqkv_l + (size_t)2*H_*H_, H_, H_, 0, 0);
      transpose_f16_k<float><<<dim3(H_/32, H_/32, 1), 256, 0, stream>>>(
          Wo + (size_t)l*H_*H_, wo_l, H_, H_, 0, 0);
      transpose_f16_k<float><<<dim3(FF_/32, H_/32, 1), 256, 0, stream>>>(
          W1 + (size_t)l*H_*FF_, w1_l, FF_, H_, 0, 0);
      transpose_f16_k<float><<<dim3(H_/32, FF_/32, 1), 256, 0, stream>>>(
          W2 + (size_t)l*FF_*H_, w2_l, H_, FF_, 0, 0);
    }
    // fused QKV projection (single-buf 128x128, 3 blocks/CU); V cols -> vT
    gemm2_k<128,128,0,1,1,1><<<dim3(QKVN_/128, MTOK_/128, 1), 256, 0, stream>>>(
        h16, wqkv_l, qkv, bqkv + (size_t)l*QKVN_, vT, rowmap, meta, H_, H_, QKVN_, H_, 1.0f);
    // fused flash attention -> ctx16
    fattn_k<<<dim3(B_*NH_, S_/128), 256, 0, stream>>>(qkv, vT, ctx16, lenb);
    // O projection (single-buf 64x64, 16KB -> deep TLP) -> tmp16, then LN
    gemm2_k<64,64,0,1,1,0><<<dim3(H_/64, MTOK_/64, 1), 256, 0, stream>>>(
        ctx16, wo_l, tmp16, bo + (size_t)l*H_, nullptr, rowmap, meta, H_, H_, H_, H_, 1.0f);
    ln_res_k<<<MTOK_/4, 256, 0, stream>>>(h32, tmp16, l1s + (size_t)l*H_, l1b + (size_t)l*H_, h16, rowmap, meta);
    // FFN: FF1 single-buf 128x128, FF2 single-buf 64x64
    gemm2_k<128,128,1,1,1,0><<<dim3(FF_/128, MTOK_/128, 1), 256, 0, stream>>>(
        h16, w1_l, ff16, b1 + (size_t)l*FF_, nullptr, rowmap, meta, H_, H_, FF_, H_, 1.0f);
    gemm2_k<64,64,0,1,1,0><<<dim3(H_/64, MTOK_/64, 1), 256, 0, stream>>>(
        ff16, w2_l, tmp16, b2 + (size_t)l*H_, nullptr, rowmap, meta, FF_, FF_, H_, FF_, 1.0f);
    ln_res_k<<<MTOK_/4, 256, 0, stream>>>(h32, tmp16, l2s + (size_t)l*H_, l2b + (size_t)l*H_, h16, rowmap, meta);
  }

  // projection to word dims (compacted M)
  gemm2_k<64,64,0,0,1,0><<<dim3(WD_/64, MTOK_/64, 1), 256, 0, stream>>>(
      h16, pwT, proj32, pb, nullptr, rowmap, meta, H_, H_, WD_, H_, 1.0f);
  merge_k<<<dim3(W_, B_), 256, 0, stream>>>(proj32, tlens,
      (float*)d_out, (float*)d_out + (size_t)B_ * W_ * WD_);
}

// Round 12
// 2283.569 us; speedup vs baseline: 1.0843x; 1.0265x over previous
//
#include <hip/hip_runtime.h>
#include <stdint.h>

#define B_ 16
#define S_ 512
#define H_ 768
#define L_ 12
#define NH_ 12
#define DH_ 64
#define FF_ 3072
#define WD_ 256
#define W_ 255
#define MTOK_ (B_*S_)
#define QKVN_ 2304
#define MPADR_ 128   // dummy pad rows appended to row-indexed buffers

typedef _Float16 f16;
typedef _Float16 f16x8 __attribute__((ext_vector_type(8)));
typedef _Float16 f16x4 __attribute__((ext_vector_type(4)));
typedef _Float16 f16x2 __attribute__((ext_vector_type(2)));
typedef float f32x4 __attribute__((ext_vector_type(4)));

#define SCHED_FENCE() __builtin_amdgcn_sched_barrier(0)

// tanh-form gelu via exp-sigmoid; max |dev| vs exact ~7e-4 (threshold margin 3x)
__device__ __forceinline__ float gelu_fast(float x) {
  float u = x * (1.0f + 0.044715f * x * x);
  float e = __expf(-1.5957691216f * u);
  return __fdividef(x, 1.0f + e);
}

__device__ __forceinline__ void gload16(const f16* g, f16* l) {
  __builtin_amdgcn_global_load_lds(
      (const __attribute__((address_space(1))) void*)g,
      (__attribute__((address_space(3))) void*)l, 16, 0, 0);
}

// Row-compacted GEMM, SINGLE-buffered m97 structure. SPLITK>1: blockIdx.z
// selects K-chunk; chunk z writes (f16*)Cv + z*czoff; bias only on z=0.
// Early exit on ORIGINAL flat id (dead tail XCD-balanced), bijective XCD
// swizzle within live count. QKVW=1: cols >= 2*H_ -> vT[bh][d][s].
template<int BM, int BN, int ACT, int OUTF16, int BIAS, int QKVW, int SPLITK>
__global__ __launch_bounds__(256) void gemm2_k(
    const f16* __restrict__ A, const f16* __restrict__ Bm, void* __restrict__ Cv,
    const float* __restrict__ bias, f16* __restrict__ vTp,
    const int* __restrict__ rowmap, const int* __restrict__ meta,
    int lda, int ldb, int ldc, int K, float scale, long czoff)
{
  constexpr int MI = BM / 32;
  constexpr int NI = BN / 32;
  const int gx = gridDim.x;
  int flat = blockIdx.y * gx + blockIdx.x;
  const int nlive = (meta[1] / BM) * gx;
  if (flat >= nlive) return;                // uniform: whole block exits pre-barrier
  {
    int q = nlive >> 3, r = nlive & 7;
    int xcd = flat & 7, idx = flat >> 3;
    flat = (xcd < r ? xcd * (q + 1) : r * (q + 1) + (xcd - r) * q) + idx;
  }
  const int row0 = (flat / gx) * BM;
  const int col0 = (flat % gx) * BN;
  const int z = (SPLITK > 1) ? blockIdx.z : 0;
  const int kc_len = K / SPLITK;
  A  += (size_t)z * kc_len;
  Bm += (size_t)z * kc_len;

  __shared__ __align__(16) f16 lA[BM * 64];
  __shared__ __align__(16) f16 lB[BN * 64];
  const int lane = threadIdx.x & 63;
  const int wave = threadIdx.x >> 6;
  const int wr = wave >> 1, wc = wave & 1;
  const int srow = lane >> 3;
  const int scol = lane & 7;
  const int cs = scol ^ srow;

  int arow[BM / 32];
#pragma unroll
  for (int i = 0; i < BM / 32; ++i)
    arow[i] = rowmap[row0 + (wave * (BM / 32) + i) * 8 + srow];

  f32x4 acc[MI][NI] = {};
  const int nt = kc_len >> 6;
  const int rl = lane & 15, g = lane >> 4;
  for (int t = 0; t < nt; ++t) {
    __syncthreads();                        // all waves done reading previous tile
    const int k0 = t * 64;
#pragma unroll
    for (int i = 0; i < BM / 32; ++i) {
      int seg = wave * (BM / 32) + i;
      gload16(&A[(size_t)arow[i] * lda + k0 + cs * 8], &lA[seg * 512]);
    }
#pragma unroll
    for (int i = 0; i < BN / 32; ++i) {
      int seg = wave * (BN / 32) + i;
      gload16(&Bm[(size_t)(col0 + seg * 8 + srow) * ldb + k0 + cs * 8], &lB[seg * 512]);
    }
    __syncthreads();                        // drains vmcnt(0): tile landed
#pragma unroll
    for (int c = 0; c < 2; ++c) {
      f16x8 af[MI], bf[NI];
#pragma unroll
      for (int mi = 0; mi < MI; ++mi) {
        int r = wr * (MI * 16) + mi * 16 + rl;
        int u = (c * 4 + g) ^ (r & 7);
        af[mi] = *(const f16x8*)&lA[r * 64 + u * 8];
      }
#pragma unroll
      for (int ni = 0; ni < NI; ++ni) {
        int r = wc * (NI * 16) + ni * 16 + rl;
        int u = (c * 4 + g) ^ (r & 7);
        bf[ni] = *(const f16x8*)&lB[r * 64 + u * 8];
      }
#pragma unroll
      for (int mi = 0; mi < MI; ++mi)
#pragma unroll
        for (int ni = 0; ni < NI; ++ni)
          acc[mi][ni] = __builtin_amdgcn_mfma_f32_16x16x32_f16(af[mi], bf[ni], acc[mi][ni], 0, 0, 0);
    }
  }
  // epilogue: C/D layout col=lane&15, row=(lane>>4)*4+reg; rows via rowmap
  const int cl = lane & 15;
  const int rq = (lane >> 4) * 4;
#pragma unroll
  for (int mi = 0; mi < MI; ++mi) {
    const int4 rm4 = *(const int4*)&rowmap[row0 + wr * (MI * 16) + mi * 16 + rq];
    const int rows[4] = { rm4.x, rm4.y, rm4.z, rm4.w };
    const bool contig = (rm4.w == rm4.x + 3) && ((rm4.x & 3) == 0);
#pragma unroll
    for (int ni = 0; ni < NI; ++ni) {
      int col = col0 + wc * (NI * 16) + ni * 16 + cl;
      float bv = 0.f;
      if constexpr (BIAS) { if (SPLITK == 1 || z == 0) bv = bias[col]; }
      if constexpr (QKVW) {
        if (col >= 2 * H_) {                 // transposed V write: vT[bh][d][s]
          int vc = col - 2 * H_;
          int h = vc >> 6, d = vc & 63;
          if (contig) {
            if (rm4.x < MTOK_) {
              int b = rm4.x >> 9, s = rm4.x & (S_ - 1);
              f16x4 o4;
#pragma unroll
              for (int r = 0; r < 4; ++r) o4[r] = (f16)(acc[mi][ni][r] * scale + bv);
              *(f16x4*)&vTp[(((size_t)(b * NH_ + h)) * DH_ + d) * S_ + s] = o4;
            }
          } else {
#pragma unroll
            for (int r = 0; r < 4; ++r) {
              int orow = rows[r];
              if (orow < MTOK_) {
                int b = orow >> 9, s = orow & (S_ - 1);
                vTp[(((size_t)(b * NH_ + h)) * DH_ + d) * S_ + s] = (f16)(acc[mi][ni][r] * scale + bv);
              }
            }
          }
          continue;
        }
      }
#pragma unroll
      for (int r = 0; r < 4; ++r) {
        float v = acc[mi][ni][r] * scale + bv;
        if constexpr (ACT == 1) v = gelu_fast(v);
        if constexpr (OUTF16) {
          ((f16*)Cv + (size_t)z * czoff)[(size_t)rows[r] * ldc + col] = (f16)v;
        } else {
          ((float*)Cv)[(size_t)rows[r] * ldc + col] = v;
        }
      }
    }
  }
}

// Fused flash attention with issue-early staging + counted vmcnt (1-ahead).
// grid (b*NH, qtile). Swapped QK^T -> S^T acc. No-max softmax.
__global__ __launch_bounds__(256) void fattn_k(
    const f16* __restrict__ qkv, const f16* __restrict__ vT,
    f16* __restrict__ ctx, const int* __restrict__ lenp)
{
  const int bh = blockIdx.x, qt = blockIdx.y;
  const int b = bh / NH_, h = bh - b * NH_;
  const int L = lenp[b];
  if ((qt << 7) >= L) return;               // uniform per block
  const int nkt = (L + 63) >> 6;
  const int lane = threadIdx.x & 63, wave = threadIdx.x >> 6;
  const int rl = lane & 15, g = lane >> 4;
  const int srow = lane >> 3, scol = lane & 7;
  const int cs = scol ^ srow;

  __shared__ __align__(16) f16 lK[2][64 * 64];
  __shared__ __align__(16) f16 lV[2][64 * 64];
  __shared__ __align__(16) f16 lP[128 * 72];

  auto stage = [&](int p, int kt) {       // 4 gload16 per wave
#pragma unroll
    for (int i = 0; i < 2; ++i) {
      int seg = wave * 2 + i;
      int r = seg * 8 + srow;
      gload16(&qkv[((size_t)b * S_ + kt * 64 + r) * QKVN_ + H_ + h * DH_ + cs * 8], &lK[p][seg * 512]);
      gload16(&vT[((size_t)bh * DH_ + r) * S_ + kt * 64 + cs * 8], &lV[p][seg * 512]);
    }
  };

  const size_t qrow0 = (size_t)b * S_ + qt * 128 + wave * 32;
  f16x8 qf[2][2];
#pragma unroll
  for (int bq = 0; bq < 2; ++bq)
#pragma unroll
    for (int kc = 0; kc < 2; ++kc)
      qf[bq][kc] = *(const f16x8*)&qkv[(qrow0 + bq * 16 + rl) * QKVN_ + h * DH_ + kc * 32 + g * 8];

  float lsum[2] = {0.f, 0.f};
  f32x4 accO[2][4] = {};

  stage(0, 0);
  for (int kt = 0; kt < nkt; ++kt) {
    if (kt + 1 < nkt) {
      stage((kt + 1) & 1, kt + 1);
      asm volatile("s_waitcnt vmcnt(4) lgkmcnt(0)" ::: "memory");
    } else {
      asm volatile("s_waitcnt vmcnt(0) lgkmcnt(0)" ::: "memory");
    }
    SCHED_FENCE();
    __builtin_amdgcn_s_barrier();           // B1: all stage(kt) complete
    SCHED_FENCE();
    const int p = kt & 1;

    f32x4 accS[4][2] = {};
    __builtin_amdgcn_s_setprio(1);
#pragma unroll
    for (int kc = 0; kc < 2; ++kc) {
#pragma unroll
      for (int ak = 0; ak < 4; ++ak) {
        int row = ak * 16 + rl;
        int u = (kc * 4 + g) ^ (row & 7);
        f16x8 kf = *(const f16x8*)&lK[p][row * 64 + u * 8];
#pragma unroll
        for (int bq = 0; bq < 2; ++bq)
          accS[ak][bq] = __builtin_amdgcn_mfma_f32_16x16x32_f16(kf, qf[bq][kc], accS[ak][bq], 0, 0, 0);
      }
    }
    __builtin_amdgcn_s_setprio(0);

    const int kvb = kt * 64 + g * 4;
#pragma unroll
    for (int bq = 0; bq < 2; ++bq) {
      float pv[16];
      float ps = 0.f;
#pragma unroll
      for (int ak = 0; ak < 4; ++ak)
#pragma unroll
        for (int r = 0; r < 4; ++r) {
          float s = accS[ak][bq][r] * 0.125f;
          float pp = (kvb + ak * 16 + r < L) ? __expf(s) : 0.f;
          pv[ak * 4 + r] = pp;
          ps += pp;
        }
      ps += __shfl_xor(ps, 16);
      ps += __shfl_xor(ps, 32);
      lsum[bq] += ps;
      const int qrow = wave * 32 + bq * 16 + rl;
#pragma unroll
      for (int ak = 0; ak < 4; ++ak)
#pragma unroll
        for (int r2 = 0; r2 < 2; ++r2) {
          f16x2 pk = { (f16)pv[ak * 4 + r2 * 2], (f16)pv[ak * 4 + r2 * 2 + 1] };
          *(f16x2*)&lP[qrow * 72 + ak * 16 + g * 4 + r2 * 2] = pk;
        }
    }
    __builtin_amdgcn_s_setprio(1);
#pragma unroll
    for (int kc = 0; kc < 2; ++kc) {
      f16x8 pa[2], vf[4];
#pragma unroll
      for (int aq = 0; aq < 2; ++aq) {
        int prow = wave * 32 + aq * 16 + rl;
        pa[aq] = *(const f16x8*)&lP[prow * 72 + kc * 32 + g * 8];
      }
#pragma unroll
      for (int bd = 0; bd < 4; ++bd) {
        int vrow = bd * 16 + rl;
        int u = (kc * 4 + g) ^ (vrow & 7);
        vf[bd] = *(const f16x8*)&lV[p][vrow * 64 + u * 8];
      }
#pragma unroll
      for (int aq = 0; aq < 2; ++aq)
#pragma unroll
        for (int bd = 0; bd < 4; ++bd)
          accO[aq][bd] = __builtin_amdgcn_mfma_f32_16x16x32_f16(pa[aq], vf[bd], accO[aq][bd], 0, 0, 0);
    }
    __builtin_amdgcn_s_setprio(0);
    SCHED_FENCE();
    asm volatile("s_waitcnt lgkmcnt(0)" ::: "memory");
    SCHED_FENCE();
    __builtin_amdgcn_s_barrier();           // B2: all reads of buf[kt&1] done
    SCHED_FENCE();
  }

  float linv[2] = { 1.f / lsum[0], 1.f / lsum[1] };
  const size_t orow0 = (size_t)b * S_ + qt * 128 + wave * 32;
#pragma unroll
  for (int aq = 0; aq < 2; ++aq)
#pragma unroll
    for (int r = 0; r < 4; ++r) {
      float li = __shfl(linv[aq], (lane & 48) | (g * 4 + r));
      int q = aq * 16 + g * 4 + r;
#pragma unroll
      for (int bd = 0; bd < 4; ++bd)
        ctx[(orow0 + q) * H_ + h * DH_ + bd * 16 + rl] = (f16)(accO[aq][bd][r] * li);
    }
}

// out[n*ldout + k] = (f16) in[k*ldin + n]; 32x32 tiles, batched via z.
template<typename TI>
__global__ __launch_bounds__(256) void transpose_f16_k(
    const TI* __restrict__ in, f16* __restrict__ out,
    int ldin, int ldout, long i1, long o1)
{
  const int z = blockIdx.z;
  in  += (size_t)z * i1;
  out += (size_t)z * o1;
  __shared__ float t[32][33];
  const int kt = blockIdx.y * 32, nt = blockIdx.x * 32;
  const int tx = threadIdx.x & 31, tg = threadIdx.x >> 5;
#pragma unroll
  for (int i = 0; i < 4; ++i) {
    int k = tg * 4 + i;
    t[k][tx] = (float)in[(size_t)(kt + k) * ldin + nt + tx];
  }
  __syncthreads();
#pragma unroll
  for (int i = 0; i < 4; ++i) {
    int n = tg * 4 + i;
    out[(size_t)(nt + n) * ldout + kt + tx] = (f16)t[tx][n];
  }
}

__global__ void bias_cat_k(const float* __restrict__ bq, const float* __restrict__ bk,
                           const float* __restrict__ bv, float* __restrict__ out) {
  const int l = blockIdx.y;
  const int j = blockIdx.x * 256 + threadIdx.x;
  float v = (j < H_) ? bq[l * H_ + j] : (j < 2 * H_) ? bk[l * H_ + j - H_] : bv[l * H_ + j - 2 * H_];
  out[l * QKVN_ + j] = v;
}

// embed + LN -> h16 (f16 residual stream)
__global__ __launch_bounds__(256) void embed_ln_k(
    const int* __restrict__ ids, const float* __restrict__ wemb,
    const float* __restrict__ pemb, const float* __restrict__ temb,
    const float* __restrict__ lns, const float* __restrict__ lnb,
    f16* __restrict__ h16)
{
  const int row = blockIdx.x * 4 + (threadIdx.x >> 6);
  const int lane = threadIdx.x & 63;
  const int s = row & (S_ - 1);
  const float4* wp = (const float4*)(wemb + (size_t)ids[row] * H_);
  const float4* pp = (const float4*)(pemb + (size_t)s * H_);
  const float4* tp = (const float4*)temb;
  float4 x[3]; float sm = 0.f, sq = 0.f;
#pragma unroll
  for (int j = 0; j < 3; ++j) {
    int i4 = lane + 64 * j;
    float4 a = wp[i4], bb = pp[i4], c = tp[i4];
    float4 v; v.x = a.x + bb.x + c.x; v.y = a.y + bb.y + c.y;
    v.z = a.z + bb.z + c.z; v.w = a.w + bb.w + c.w;
    x[j] = v;
    sm += v.x + v.y + v.z + v.w;
    sq += v.x * v.x + v.y * v.y + v.z * v.z + v.w * v.w;
  }
#pragma unroll
  for (int o = 32; o > 0; o >>= 1) { sm += __shfl_xor(sm, o); sq += __shfl_xor(sq, o); }
  float mean = sm * (1.f / H_);
  float inv = rsqrtf(sq * (1.f / H_) - mean * mean + 1e-12f);
  f16* ho = h16 + (size_t)row * H_;
#pragma unroll
  for (int j = 0; j < 3; ++j) {
    int i4 = lane + 64 * j;
    float4 sc = ((const float4*)lns)[i4], bi = ((const float4*)lnb)[i4];
    float4 v = x[j];
    f16x4 o4 = {(f16)((v.x - mean) * inv * sc.x + bi.x),
                (f16)((v.y - mean) * inv * sc.y + bi.y),
                (f16)((v.z - mean) * inv * sc.z + bi.z),
                (f16)((v.w - mean) * inv * sc.w + bi.w)};
    *(f16x4*)&ho[i4 * 4] = o4;
  }
}

// compacted residual(h16 + tmpA + tmpB) -> LN -> h16 (f16 residual stream)
__global__ __launch_bounds__(256) void ln_res_k(
    f16* __restrict__ h16, const f16* __restrict__ tmpA, const f16* __restrict__ tmpB,
    const float* __restrict__ lns, const float* __restrict__ lnb,
    const int* __restrict__ rowmap, const int* __restrict__ meta)
{
  const int crow = blockIdx.x * 4 + (threadIdx.x >> 6);
  if (crow >= meta[0]) return;
  const int row = rowmap[crow];
  const int lane = threadIdx.x & 63;
  const f16x4* hp = (const f16x4*)(h16 + (size_t)row * H_);
  const f16x4* ta = (const f16x4*)(tmpA + (size_t)row * H_);
  const f16x4* tb = (const f16x4*)(tmpB + (size_t)row * H_);
  float4 x[3]; float sm = 0.f, sq = 0.f;
#pragma unroll
  for (int j = 0; j < 3; ++j) {
    int i4 = lane + 64 * j;
    f16x4 a = hp[i4], va = ta[i4], vb = tb[i4];
    float4 v;
    v.x = (float)a[0] + (float)va[0] + (float)vb[0];
    v.y = (float)a[1] + (float)va[1] + (float)vb[1];
    v.z = (float)a[2] + (float)va[2] + (float)vb[2];
    v.w = (float)a[3] + (float)va[3] + (float)vb[3];
    x[j] = v;
    sm += v.x + v.y + v.z + v.w;
    sq += v.x * v.x + v.y * v.y + v.z * v.z + v.w * v.w;
  }
#pragma unroll
  for (int o = 32; o > 0; o >>= 1) { sm += __shfl_xor(sm, o); sq += __shfl_xor(sq, o); }
  float mean = sm * (1.f / H_);
  float inv = rsqrtf(sq * (1.f / H_) - mean * mean + 1e-12f);
  f16* ho = h16 + (size_t)row * H_;
#pragma unroll
  for (int j = 0; j < 3; ++j) {
    int i4 = lane + 64 * j;
    float4 sc = ((const float4*)lns)[i4], bi = ((const float4*)lnb)[i4];
    float4 v = x[j];
    f16x4 o4 = {(f16)((v.x - mean) * inv * sc.x + bi.x),
                (f16)((v.y - mean) * inv * sc.y + bi.y),
                (f16)((v.z - mean) * inv * sc.z + bi.z),
                (f16)((v.w - mean) * inv * sc.w + bi.w)};
    *(f16x4*)&ho[i4 * 4] = o4;
  }
}

// fused: per-batch valid lengths + meta {Mv, Mpad} + compact->orig rowmap
__global__ void lenmap_k(const int* __restrict__ mask, int* __restrict__ len,
                         int* __restrict__ meta, int* __restrict__ rowmap) {
  const int t = threadIdx.x;   // 512
  __shared__ int red[512];
  __shared__ int cum[17];
  const int b = t >> 5, sl = t & 31;   // 32 lanes per batch
  int part = 0;
#pragma unroll
  for (int j = 0; j < 16; ++j) part += mask[b * S_ + sl + 32 * j];
  red[t] = part; __syncthreads();
  for (int o = 16; o > 0; o >>= 1) {
    if (sl < o) red[t] += red[t + o];
    __syncthreads();
  }
  if (t == 0) {
    int c = 0; cum[0] = 0;
    for (int bb = 0; bb < B_; ++bb) { len[bb] = red[bb * 32]; c += red[bb * 32]; cum[bb + 1] = c; }
    meta[0] = c;
    meta[1] = (c + 127) & ~127;
  }
  __syncthreads();
  const int Mv = cum[16];
  for (int i = t; i < MTOK_ + MPADR_; i += 512) {
    int orig;
    if (i < Mv) {
      int bb = 0;
#pragma unroll
      for (int k = 1; k <= 16; ++k) bb += (i >= cum[k]) ? 1 : 0;
      orig = bb * S_ + (i - cum[bb]);
    } else {
      int d = i - Mv;
      orig = MTOK_ + (d < MPADR_ ? d : MPADR_ - 1);
    }
    rowmap[i] = orig;
  }
}

__global__ __launch_bounds__(256) void merge_k(
    const float* __restrict__ proj, const int* __restrict__ tl,
    float* __restrict__ means, float* __restrict__ masks)
{
  const int w = blockIdx.x, b = blockIdx.y;
  const int t = threadIdx.x;
  __shared__ int red[256];
  int part = 0;
  for (int j = t; j < w; j += 256) part += tl[b * W_ + j];
  red[t] = part; __syncthreads();
  for (int o = 128; o > 0; o >>= 1) { if (t < o) red[t] += red[t + o]; __syncthreads(); }
  const int start = red[0];
  const int len = tl[b * W_ + w];
  float s = 0.f;
  for (int l = 0; l < len; ++l)
    s += proj[((size_t)b * S_ + 1 + start + l) * WD_ + t];
  means[((size_t)b * W_ + w) * WD_ + t] = (len > 0) ? s / (float)len : 0.f;
  if (t == 0) masks[b * W_ + w] = (len > 0) ? 1.f : 0.f;
}

extern "C" void kernel_launch(void* const* d_in, const int* in_sizes, int n_in,
                              void* d_out, int out_size, void* d_ws, size_t ws_size,
                              hipStream_t stream)
{
  (void)in_sizes; (void)n_in; (void)out_size;
  const int*   ids   = (const int*)d_in[0];
  const int*   amask = (const int*)d_in[1];
  const int*   tlens = (const int*)d_in[2];
  const float* wemb  = (const float*)d_in[3];
  const float* pemb  = (const float*)d_in[4];
  const float* temb  = (const float*)d_in[5];
  const float* elns  = (const float*)d_in[6];
  const float* elnb  = (const float*)d_in[7];
  const float* Wq = (const float*)d_in[8];  const float* bq = (const float*)d_in[9];
  const float* Wk = (const float*)d_in[10]; const float* bk = (const float*)d_in[11];
  const float* Wv = (const float*)d_in[12]; const float* bv = (const float*)d_in[13];
  const float* Wo = (const float*)d_in[14]; const float* bo = (const float*)d_in[15];
  const float* l1s = (const float*)d_in[16]; const float* l1b = (const float*)d_in[17];
  const float* W1 = (const float*)d_in[18]; const float* b1 = (const float*)d_in[19];
  const float* W2 = (const float*)d_in[20]; const float* b2 = (const float*)d_in[21];
  const float* l2s = (const float*)d_in[22]; const float* l2b = (const float*)d_in[23];
  const float* pW = (const float*)d_in[24]; const float* pb = (const float*)d_in[25];

  const int MR = MTOK_ + MPADR_;   // rows incl. dummy pad region
  char* ws = (char*)d_ws;
  size_t off = 0;
  auto alloc = [&](size_t n) { void* r = ws + off; off += (n + 255) & ~(size_t)255; return r; };
  f16*   h16   = (f16*)alloc((size_t)MR * H_ * 2);
  f16*   qkv   = (f16*)alloc((size_t)MR * QKVN_ * 2);
  f16*   ctx16 = (f16*)alloc((size_t)MR * H_ * 2);
  f16*   vT    = (f16*)alloc((size_t)B_ * NH_ * DH_ * S_ * 2);
  f16*   ff16  = (f16*)alloc((size_t)MR * FF_ * 2);
  f16*   tmp16 = (f16*)alloc((size_t)MR * H_ * 2 * 2);   // 2 split-K halves
  float* proj32 = (float*)alloc((size_t)MR * WD_ * 4);
  f16*   pwT   = (f16*)alloc((size_t)WD_ * H_ * 2);
  float* bqkv  = (float*)alloc((size_t)L_ * QKVN_ * 4);
  int*   lenb  = (int*)alloc(256);
  int*   meta  = (int*)alloc(256);
  int*   rowmap = (int*)alloc((size_t)MR * 4);
  f16*   tmp16b = tmp16 + (size_t)MR * H_;

  const size_t wqkv_sz = (size_t)QKVN_ * H_ * 2;
  const size_t wo_sz   = (size_t)H_ * H_ * 2;
  const size_t w1_sz   = (size_t)H_ * FF_ * 2;
  const size_t w2_sz   = (size_t)FF_ * H_ * 2;
  const size_t per_layer_w = wqkv_sz + wo_sz + w1_sz + w2_sz;
  const bool big = ws_size >= off + (size_t)L_ * per_layer_w + 8192;
  const int nz = big ? L_ : 1;
  f16* wqkv0 = (f16*)alloc((size_t)nz * wqkv_sz);
  f16* wo0   = (f16*)alloc((size_t)nz * wo_sz);
  f16* w10   = (f16*)alloc((size_t)nz * w1_sz);
  f16* w20   = (f16*)alloc((size_t)nz * w2_sz);

  lenmap_k<<<1, 512, 0, stream>>>(amask, lenb, meta, rowmap);
  embed_ln_k<<<MTOK_ / 4, 256, 0, stream>>>(ids, wemb, pemb, temb, elns, elnb, h16);
  transpose_f16_k<float><<<dim3(WD_/32, H_/32, 1), 256, 0, stream>>>(pW, pwT, WD_, H_, 0, 0);
  bias_cat_k<<<dim3(QKVN_/256, L_), 256, 0, stream>>>(bq, bk, bv, bqkv);

  if (big) {
    transpose_f16_k<float><<<dim3(H_/32, H_/32, L_), 256, 0, stream>>>(
        Wq, wqkv0,                   H_, H_, (long)H_*H_, (long)QKVN_*H_);
    transpose_f16_k<float><<<dim3(H_/32, H_/32, L_), 256, 0, stream>>>(
        Wk, wqkv0 + (size_t)H_*H_,   H_, H_, (long)H_*H_, (long)QKVN_*H_);
    transpose_f16_k<float><<<dim3(H_/32, H_/32, L_), 256, 0, stream>>>(
        Wv, wqkv0 + (size_t)2*H_*H_, H_, H_, (long)H_*H_, (long)QKVN_*H_);
    transpose_f16_k<float><<<dim3(H_/32, H_/32, L_), 256, 0, stream>>>(
        Wo, wo0, H_, H_, (long)H_*H_, (long)H_*H_);
    transpose_f16_k<float><<<dim3(FF_/32, H_/32, L_), 256, 0, stream>>>(
        W1, w10, FF_, H_, (long)H_*FF_, (long)H_*FF_);
    transpose_f16_k<float><<<dim3(H_/32, FF_/32, L_), 256, 0, stream>>>(
        W2, w20, H_, FF_, (long)FF_*H_, (long)FF_*H_);
  }

  for (int l = 0; l < L_; ++l) {
    f16* wqkv_l = wqkv0 + (size_t)(big ? l : 0) * QKVN_ * H_;
    f16* wo_l   = wo0   + (size_t)(big ? l : 0) * H_ * H_;
    f16* w1_l   = w10   + (size_t)(big ? l : 0) * H_ * FF_;
    f16* w2_l   = w20   + (size_t)(big ? l : 0) * FF_ * H_;
    if (!big) {
      transpose_f16_k<float><<<dim3(H_/32, H_/32, 1), 256, 0, stream>>>(
          Wq + (size_t)l*H_*H_, wqkv_l,                   H_, H_, 0, 0);
      transpose_f16_k<float><<<dim3(H_/32, H_/32, 1), 256, 0, stream>>>(
          Wk + (size_t)l*H_*H_, wqkv_l + (size_t)H_*H_,   H_, H_, 0, 0);
      transpose_f16_k<float><<<dim3(H_/32, H_/32, 1), 256, 0, stream>>>(
          Wv + (size_t)l*H_*H_, wqkv_l + (size_t)2*H_*H_, H_, H_, 0, 0);
      transpose_f16_k<float><<<dim3(H_/32, H_/32, 1), 256, 0, stream>>>(
          Wo + (size_t)l*H_*H_, wo_l, H_, H_, 0, 0);
      transpose_f16_k<float><<<dim3(FF_/32, H_/32, 1), 256, 0, stream>>>(
          W1 + (size_t)l*H_*FF_, w1_l, FF_, H_, 0, 0);
      transpose_f16_k<float><<<dim3(H_/32, FF_/32, 1), 256, 0, stream>>>(
          W2 + (size_t)l*FF_*H_, w2_l, H_, FF_, 0, 0);
    }
    // fused QKV projection (single-buf 128x128); V cols -> vT transposed
    gemm2_k<128,128,0,1,1,1,1><<<dim3(QKVN_/128, MTOK_/128, 1), 256, 0, stream>>>(
        h16, wqkv_l, qkv, bqkv + (size_t)l*QKVN_, vT, rowmap, meta, H_, H_, QKVN_, H_, 1.0f, 0);
    // fused flash attention -> ctx16
    fattn_k<<<dim3(B_*NH_, S_/128), 256, 0, stream>>>(qkv, vT, ctx16, lenb);
    // O projection: single-buf 64x64 split-K=2 -> tmp16/tmp16b, then LN
    gemm2_k<64,64,0,1,1,0,2><<<dim3(H_/64, MTOK_/64, 2), 256, 0, stream>>>(
        ctx16, wo_l, tmp16, bo + (size_t)l*H_, nullptr, rowmap, meta, H_, H_, H_, H_, 1.0f, (long)MR * H_);
    ln_res_k<<<MTOK_/4, 256, 0, stream>>>(h16, tmp16, tmp16b, l1s + (size_t)l*H_, l1b + (size_t)l*H_, rowmap, meta);
    // FFN: FF1 single-buf 128x128; FF2 single-buf 64x64 split-K=2
    gemm2_k<128,128,1,1,1,0,1><<<dim3(FF_/128, MTOK_/128, 1), 256, 0, stream>>>(
        h16, w1_l, ff16, b1 + (size_t)l*FF_, nullptr, rowmap, meta, H_, H_, FF_, H_, 1.0f, 0);
    gemm2_k<64,64,0,1,1,0,2><<<dim3(H_/64, MTOK_/64, 2), 256, 0, stream>>>(
        ff16, w2_l, tmp16, b2 + (size_t)l*H_, nullptr, rowmap, meta, FF_, FF_, H_, FF_, 1.0f, (long)MR * H_);
    ln_res_k<<<MTOK_/4, 256, 0, stream>>>(h16, tmp16, tmp16b, l2s + (size_t)l*H_, l2b + (size_t)l*H_, rowmap, meta);
  }

  // projection to word dims (compacted M)
  gemm2_k<64,64,0,0,1,0,1><<<dim3(WD_/64, MTOK_/64, 1), 256, 0, stream>>>(
      h16, pwT, proj32, pb, nullptr, rowmap, meta, H_, H_, WD_, H_, 1.0f, 0);
  merge_k<<<dim3(W_, B_), 256, 0, stream>>>(proj32, tlens,
      (float*)d_out, (float*)d_out + (size_t)B_ * W_ * WD_);
}

// Round 13
// 2259.179 us; speedup vs baseline: 1.0960x; 1.0108x over previous
//
#include <hip/hip_runtime.h>
#include <stdint.h>

#define B_ 16
#define S_ 512
#define H_ 768
#define L_ 12
#define NH_ 12
#define DH_ 64
#define FF_ 3072
#define WD_ 256
#define W_ 255
#define MTOK_ (B_*S_)
#define QKVN_ 2304
#define MPADR_ 128   // dummy pad rows appended to row-indexed buffers

typedef _Float16 f16;
typedef _Float16 f16x8 __attribute__((ext_vector_type(8)));
typedef _Float16 f16x4 __attribute__((ext_vector_type(4)));
typedef _Float16 f16x2 __attribute__((ext_vector_type(2)));
typedef float f32x4 __attribute__((ext_vector_type(4)));

#define SCHED_FENCE() __builtin_amdgcn_sched_barrier(0)

// tanh-form gelu via exp-sigmoid; max |dev| vs exact ~7e-4 (threshold margin 3x)
__device__ __forceinline__ float gelu_fast(float x) {
  float u = x * (1.0f + 0.044715f * x * x);
  float e = __expf(-1.5957691216f * u);
  return __fdividef(x, 1.0f + e);
}

__device__ __forceinline__ void gload16(const f16* g, f16* l) {
  __builtin_amdgcn_global_load_lds(
      (const __attribute__((address_space(1))) void*)g,
      (__attribute__((address_space(3))) void*)l, 16, 0, 0);
}

// Row-compacted GEMM, SINGLE-buffered m97 structure. SPLITK>1: blockIdx.z is
// the K-chunk; chunk z writes (f16*)Cv + z*czoff; bias only on z=0.
// CIN=1: A rows are already compact (no rowmap gather). COUT=1: C rows are
// written at the compact index (contiguous). Early exit on ORIGINAL flat id
// (dead tail XCD-balanced), bijective XCD swizzle within live count.
// QKVW=1: cols >= 2*H_ -> vT[bh][d][s] (original rows).
template<int BM, int BN, int ACT, int OUTF16, int BIAS, int QKVW, int SPLITK, int CIN, int COUT>
__global__ __launch_bounds__(256) void gemm2_k(
    const f16* __restrict__ A, const f16* __restrict__ Bm, void* __restrict__ Cv,
    const float* __restrict__ bias, f16* __restrict__ vTp,
    const int* __restrict__ rowmap, const int* __restrict__ meta,
    int lda, int ldb, int ldc, int K, float scale, long czoff)
{
  constexpr int MI = BM / 32;
  constexpr int NI = BN / 32;
  const int gx = gridDim.x;
  int flat = blockIdx.y * gx + blockIdx.x;
  const int nlive = (meta[1] / BM) * gx;
  if (flat >= nlive) return;                // uniform: whole block exits pre-barrier
  {
    int q = nlive >> 3, r = nlive & 7;
    int xcd = flat & 7, idx = flat >> 3;
    flat = (xcd < r ? xcd * (q + 1) : r * (q + 1) + (xcd - r) * q) + idx;
  }
  const int row0 = (flat / gx) * BM;
  const int col0 = (flat % gx) * BN;
  const int z = (SPLITK > 1) ? blockIdx.z : 0;
  const int kc_len = K / SPLITK;
  A  += (size_t)z * kc_len;
  Bm += (size_t)z * kc_len;

  __shared__ __align__(16) f16 lA[BM * 64];
  __shared__ __align__(16) f16 lB[BN * 64];
  const int lane = threadIdx.x & 63;
  const int wave = threadIdx.x >> 6;
  const int wr = wave >> 1, wc = wave & 1;
  const int srow = lane >> 3;
  const int scol = lane & 7;
  const int cs = scol ^ srow;

  int arow[BM / 32];
#pragma unroll
  for (int i = 0; i < BM / 32; ++i) {
    int cr = row0 + (wave * (BM / 32) + i) * 8 + srow;
    arow[i] = CIN ? cr : rowmap[cr];
  }

  f32x4 acc[MI][NI] = {};
  const int nt = kc_len >> 6;
  const int rl = lane & 15, g = lane >> 4;
  for (int t = 0; t < nt; ++t) {
    __syncthreads();                        // all waves done reading previous tile
    const int k0 = t * 64;
#pragma unroll
    for (int i = 0; i < BM / 32; ++i) {
      int seg = wave * (BM / 32) + i;
      gload16(&A[(size_t)arow[i] * lda + k0 + cs * 8], &lA[seg * 512]);
    }
#pragma unroll
    for (int i = 0; i < BN / 32; ++i) {
      int seg = wave * (BN / 32) + i;
      gload16(&Bm[(size_t)(col0 + seg * 8 + srow) * ldb + k0 + cs * 8], &lB[seg * 512]);
    }
    __syncthreads();                        // drains vmcnt(0): tile landed
#pragma unroll
    for (int c = 0; c < 2; ++c) {
      f16x8 af[MI], bf[NI];
#pragma unroll
      for (int mi = 0; mi < MI; ++mi) {
        int r = wr * (MI * 16) + mi * 16 + rl;
        int u = (c * 4 + g) ^ (r & 7);
        af[mi] = *(const f16x8*)&lA[r * 64 + u * 8];
      }
#pragma unroll
      for (int ni = 0; ni < NI; ++ni) {
        int r = wc * (NI * 16) + ni * 16 + rl;
        int u = (c * 4 + g) ^ (r & 7);
        bf[ni] = *(const f16x8*)&lB[r * 64 + u * 8];
      }
#pragma unroll
      for (int mi = 0; mi < MI; ++mi)
#pragma unroll
        for (int ni = 0; ni < NI; ++ni)
          acc[mi][ni] = __builtin_amdgcn_mfma_f32_16x16x32_f16(af[mi], bf[ni], acc[mi][ni], 0, 0, 0);
    }
  }
  // epilogue: C/D layout col=lane&15, row=(lane>>4)*4+reg
  const int cl = lane & 15;
  const int rq = (lane >> 4) * 4;
#pragma unroll
  for (int mi = 0; mi < MI; ++mi) {
    const int crow0 = row0 + wr * (MI * 16) + mi * 16 + rq;
    int rows[4];
    bool contig;
    if constexpr (COUT && !QKVW) {
#pragma unroll
      for (int r = 0; r < 4; ++r) rows[r] = crow0 + r;
      contig = true;
    } else {
      const int4 rm4 = *(const int4*)&rowmap[crow0];
      rows[0] = rm4.x; rows[1] = rm4.y; rows[2] = rm4.z; rows[3] = rm4.w;
      contig = (rm4.w == rm4.x + 3) && ((rm4.x & 3) == 0);
    }
    (void)contig;
#pragma unroll
    for (int ni = 0; ni < NI; ++ni) {
      int col = col0 + wc * (NI * 16) + ni * 16 + cl;
      float bv = 0.f;
      if constexpr (BIAS) { if (SPLITK == 1 || z == 0) bv = bias[col]; }
      if constexpr (QKVW) {
        if (col >= 2 * H_) {                 // transposed V write: vT[bh][d][s]
          int vc = col - 2 * H_;
          int h = vc >> 6, d = vc & 63;
          if (contig) {
            if (rows[0] < MTOK_) {
              int b = rows[0] >> 9, s = rows[0] & (S_ - 1);
              f16x4 o4;
#pragma unroll
              for (int r = 0; r < 4; ++r) o4[r] = (f16)(acc[mi][ni][r] * scale + bv);
              *(f16x4*)&vTp[(((size_t)(b * NH_ + h)) * DH_ + d) * S_ + s] = o4;
            }
          } else {
#pragma unroll
            for (int r = 0; r < 4; ++r) {
              int orow = rows[r];
              if (orow < MTOK_) {
                int b = orow >> 9, s = orow & (S_ - 1);
                vTp[(((size_t)(b * NH_ + h)) * DH_ + d) * S_ + s] = (f16)(acc[mi][ni][r] * scale + bv);
              }
            }
          }
          continue;
        }
      }
#pragma unroll
      for (int r = 0; r < 4; ++r) {
        float v = acc[mi][ni][r] * scale + bv;
        if constexpr (ACT == 1) v = gelu_fast(v);
        if constexpr (OUTF16) {
          ((f16*)Cv + (size_t)z * czoff)[(size_t)rows[r] * ldc + col] = (f16)v;
        } else {
          ((float*)Cv)[(size_t)rows[r] * ldc + col] = v;
        }
      }
    }
  }
}

// Fused flash attention, 64-q-row blocks (wave owns 16 q rows) for 2x block
// parallelism (latency-bound regime). Issue-early staging + counted vmcnt.
// grid (b*NH, qtile of 64). Swapped QK^T -> S^T acc. No-max softmax
// (Q pre-scaled by 1/8; masked kv -> exact 0).
__global__ __launch_bounds__(256) void fattn_k(
    const f16* __restrict__ qkv, const f16* __restrict__ vT,
    f16* __restrict__ ctx, const int* __restrict__ lenp)
{
  const int bh = blockIdx.x, qt = blockIdx.y;
  const int b = bh / NH_, h = bh - b * NH_;
  const int L = lenp[b];
  if ((qt << 6) >= L) return;               // uniform per block
  const int nkt = (L + 63) >> 6;
  const int lane = threadIdx.x & 63, wave = threadIdx.x >> 6;
  const int rl = lane & 15, g = lane >> 4;
  const int srow = lane >> 3, scol = lane & 7;
  const int cs = scol ^ srow;

  __shared__ __align__(16) f16 lK[2][64 * 64];
  __shared__ __align__(16) f16 lV[2][64 * 64];
  __shared__ __align__(16) f16 lP[64 * 72];

  auto stage = [&](int p, int kt) {       // 4 gload16 per wave
#pragma unroll
    for (int i = 0; i < 2; ++i) {
      int seg = wave * 2 + i;
      int r = seg * 8 + srow;
      gload16(&qkv[((size_t)b * S_ + kt * 64 + r) * QKVN_ + H_ + h * DH_ + cs * 8], &lK[p][seg * 512]);
      gload16(&vT[((size_t)bh * DH_ + r) * S_ + kt * 64 + cs * 8], &lV[p][seg * 512]);
    }
  };

  const size_t qrow0 = (size_t)b * S_ + qt * 64 + wave * 16;
  f16x8 qf[2];
#pragma unroll
  for (int kc = 0; kc < 2; ++kc) {
    qf[kc] = *(const f16x8*)&qkv[(qrow0 + rl) * QKVN_ + h * DH_ + kc * 32 + g * 8];
    qf[kc] *= (f16)0.125f;                  // exact pow2 scale: scores = (Q/8)K
  }

  float lsum = 0.f;
  f32x4 accO[4] = {};

  stage(0, 0);
  for (int kt = 0; kt < nkt; ++kt) {
    if (kt + 1 < nkt) {
      stage((kt + 1) & 1, kt + 1);
      asm volatile("s_waitcnt vmcnt(4) lgkmcnt(0)" ::: "memory");
    } else {
      asm volatile("s_waitcnt vmcnt(0) lgkmcnt(0)" ::: "memory");
    }
    SCHED_FENCE();
    __builtin_amdgcn_s_barrier();           // B1: all stage(kt) complete
    SCHED_FENCE();
    const int p = kt & 1;

    f32x4 accS[4] = {};
    __builtin_amdgcn_s_setprio(1);
#pragma unroll
    for (int kc = 0; kc < 2; ++kc) {
#pragma unroll
      for (int ak = 0; ak < 4; ++ak) {
        int row = ak * 16 + rl;
        int u = (kc * 4 + g) ^ (row & 7);
        f16x8 kf = *(const f16x8*)&lK[p][row * 64 + u * 8];
        accS[ak] = __builtin_amdgcn_mfma_f32_16x16x32_f16(kf, qf[kc], accS[ak], 0, 0, 0);
      }
    }
    __builtin_amdgcn_s_setprio(0);

    const int kvb = kt * 64 + g * 4;
    {
      float pv[16];
      float ps = 0.f;
#pragma unroll
      for (int ak = 0; ak < 4; ++ak)
#pragma unroll
        for (int r = 0; r < 4; ++r) {
          float pp = (kvb + ak * 16 + r < L) ? __expf(accS[ak][r]) : 0.f;
          pv[ak * 4 + r] = pp;
          ps += pp;
        }
      ps += __shfl_xor(ps, 16);
      ps += __shfl_xor(ps, 32);
      lsum += ps;
      const int qrow = wave * 16 + rl;
#pragma unroll
      for (int ak = 0; ak < 4; ++ak)
#pragma unroll
        for (int r2 = 0; r2 < 2; ++r2) {
          f16x2 pk = { (f16)pv[ak * 4 + r2 * 2], (f16)pv[ak * 4 + r2 * 2 + 1] };
          *(f16x2*)&lP[qrow * 72 + ak * 16 + g * 4 + r2 * 2] = pk;
        }
    }
    __builtin_amdgcn_s_setprio(1);
#pragma unroll
    for (int kc = 0; kc < 2; ++kc) {
      f16x8 pa = *(const f16x8*)&lP[(wave * 16 + rl) * 72 + kc * 32 + g * 8];
      f16x8 vf[4];
#pragma unroll
      for (int bd = 0; bd < 4; ++bd) {
        int vrow = bd * 16 + rl;
        int u = (kc * 4 + g) ^ (vrow & 7);
        vf[bd] = *(const f16x8*)&lV[p][vrow * 64 + u * 8];
      }
#pragma unroll
      for (int bd = 0; bd < 4; ++bd)
        accO[bd] = __builtin_amdgcn_mfma_f32_16x16x32_f16(pa, vf[bd], accO[bd], 0, 0, 0);
    }
    __builtin_amdgcn_s_setprio(0);
    SCHED_FENCE();
    asm volatile("s_waitcnt lgkmcnt(0)" ::: "memory");
    SCHED_FENCE();
    __builtin_amdgcn_s_barrier();           // B2: all reads of buf[kt&1] done
    SCHED_FENCE();
  }

  float linv = 1.f / lsum;
  const size_t orow0 = (size_t)b * S_ + qt * 64 + wave * 16;
#pragma unroll
  for (int r = 0; r < 4; ++r) {
    float li = __shfl(linv, (lane & 48) | (g * 4 + r));
    int q = g * 4 + r;
#pragma unroll
    for (int bd = 0; bd < 4; ++bd)
      ctx[(orow0 + q) * H_ + h * DH_ + bd * 16 + rl] = (f16)(accO[bd][r] * li);
  }
}

// out[n*ldout + k] = (f16) in[k*ldin + n]; 32x32 tiles, batched via z.
template<typename TI>
__global__ __launch_bounds__(256) void transpose_f16_k(
    const TI* __restrict__ in, f16* __restrict__ out,
    int ldin, int ldout, long i1, long o1)
{
  const int z = blockIdx.z;
  in  += (size_t)z * i1;
  out += (size_t)z * o1;
  __shared__ float t[32][33];
  const int kt = blockIdx.y * 32, nt = blockIdx.x * 32;
  const int tx = threadIdx.x & 31, tg = threadIdx.x >> 5;
#pragma unroll
  for (int i = 0; i < 4; ++i) {
    int k = tg * 4 + i;
    t[k][tx] = (float)in[(size_t)(kt + k) * ldin + nt + tx];
  }
  __syncthreads();
#pragma unroll
  for (int i = 0; i < 4; ++i) {
    int n = tg * 4 + i;
    out[(size_t)(nt + n) * ldout + kt + tx] = (f16)t[tx][n];
  }
}

__global__ void bias_cat_k(const float* __restrict__ bq, const float* __restrict__ bk,
                           const float* __restrict__ bv, float* __restrict__ out) {
  const int l = blockIdx.y;
  const int j = blockIdx.x * 256 + threadIdx.x;
  float v = (j < H_) ? bq[l * H_ + j] : (j < 2 * H_) ? bk[l * H_ + j - H_] : bv[l * H_ + j - 2 * H_];
  out[l * QKVN_ + j] = v;
}

// embed + LN -> h16 (f16 residual stream)
__global__ __launch_bounds__(256) void embed_ln_k(
    const int* __restrict__ ids, const float* __restrict__ wemb,
    const float* __restrict__ pemb, const float* __restrict__ temb,
    const float* __restrict__ lns, const float* __restrict__ lnb,
    f16* __restrict__ h16)
{
  const int row = blockIdx.x * 4 + (threadIdx.x >> 6);
  const int lane = threadIdx.x & 63;
  const int s = row & (S_ - 1);
  const float4* wp = (const float4*)(wemb + (size_t)ids[row] * H_);
  const float4* pp = (const float4*)(pemb + (size_t)s * H_);
  const float4* tp = (const float4*)temb;
  float4 x[3]; float sm = 0.f, sq = 0.f;
#pragma unroll
  for (int j = 0; j < 3; ++j) {
    int i4 = lane + 64 * j;
    float4 a = wp[i4], bb = pp[i4], c = tp[i4];
    float4 v; v.x = a.x + bb.x + c.x; v.y = a.y + bb.y + c.y;
    v.z = a.z + bb.z + c.z; v.w = a.w + bb.w + c.w;
    x[j] = v;
    sm += v.x + v.y + v.z + v.w;
    sq += v.x * v.x + v.y * v.y + v.z * v.z + v.w * v.w;
  }
#pragma unroll
  for (int o = 32; o > 0; o >>= 1) { sm += __shfl_xor(sm, o); sq += __shfl_xor(sq, o); }
  float mean = sm * (1.f / H_);
  float inv = rsqrtf(sq * (1.f / H_) - mean * mean + 1e-12f);
  f16* ho = h16 + (size_t)row * H_;
#pragma unroll
  for (int j = 0; j < 3; ++j) {
    int i4 = lane + 64 * j;
    float4 sc = ((const float4*)lns)[i4], bi = ((const float4*)lnb)[i4];
    float4 v = x[j];
    f16x4 o4 = {(f16)((v.x - mean) * inv * sc.x + bi.x),
                (f16)((v.y - mean) * inv * sc.y + bi.y),
                (f16)((v.z - mean) * inv * sc.z + bi.z),
                (f16)((v.w - mean) * inv * sc.w + bi.w)};
    *(f16x4*)&ho[i4 * 4] = o4;
  }
}

// compacted residual(h16[orig] + tmpA[compact] + tmpB[compact]) -> LN -> h16
__global__ __launch_bounds__(256) void ln_res_k(
    f16* __restrict__ h16, const f16* __restrict__ tmpA, const f16* __restrict__ tmpB,
    const float* __restrict__ lns, const float* __restrict__ lnb,
    const int* __restrict__ rowmap, const int* __restrict__ meta)
{
  const int crow = blockIdx.x * 4 + (threadIdx.x >> 6);
  if (crow >= meta[0]) return;
  const int row = rowmap[crow];
  const int lane = threadIdx.x & 63;
  const f16x4* hp = (const f16x4*)(h16 + (size_t)row * H_);
  const f16x4* ta = (const f16x4*)(tmpA + (size_t)crow * H_);
  const f16x4* tb = (const f16x4*)(tmpB + (size_t)crow * H_);
  float4 x[3]; float sm = 0.f, sq = 0.f;
#pragma unroll
  for (int j = 0; j < 3; ++j) {
    int i4 = lane + 64 * j;
    f16x4 a = hp[i4], va = ta[i4], vb = tb[i4];
    float4 v;
    v.x = (float)a[0] + (float)va[0] + (float)vb[0];
    v.y = (float)a[1] + (float)va[1] + (float)vb[1];
    v.z = (float)a[2] + (float)va[2] + (float)vb[2];
    v.w = (float)a[3] + (float)va[3] + (float)vb[3];
    x[j] = v;
    sm += v.x + v.y + v.z + v.w;
    sq += v.x * v.x + v.y * v.y + v.z * v.z + v.w * v.w;
  }
#pragma unroll
  for (int o = 32; o > 0; o >>= 1) { sm += __shfl_xor(sm, o); sq += __shfl_xor(sq, o); }
  float mean = sm * (1.f / H_);
  float inv = rsqrtf(sq * (1.f / H_) - mean * mean + 1e-12f);
  f16* ho = h16 + (size_t)row * H_;
#pragma unroll
  for (int j = 0; j < 3; ++j) {
    int i4 = lane + 64 * j;
    float4 sc = ((const float4*)lns)[i4], bi = ((const float4*)lnb)[i4];
    float4 v = x[j];
    f16x4 o4 = {(f16)((v.x - mean) * inv * sc.x + bi.x),
                (f16)((v.y - mean) * inv * sc.y + bi.y),
                (f16)((v.z - mean) * inv * sc.z + bi.z),
                (f16)((v.w - mean) * inv * sc.w + bi.w)};
    *(f16x4*)&ho[i4 * 4] = o4;
  }
}

// fused: per-batch valid lengths + meta {Mv, Mpad} + compact->orig rowmap
__global__ void lenmap_k(const int* __restrict__ mask, int* __restrict__ len,
                         int* __restrict__ meta, int* __restrict__ rowmap) {
  const int t = threadIdx.x;   // 512
  __shared__ int red[512];
  __shared__ int cum[17];
  const int b = t >> 5, sl = t & 31;   // 32 lanes per batch
  int part = 0;
#pragma unroll
  for (int j = 0; j < 16; ++j) part += mask[b * S_ + sl + 32 * j];
  red[t] = part; __syncthreads();
  for (int o = 16; o > 0; o >>= 1) {
    if (sl < o) red[t] += red[t + o];
    __syncthreads();
  }
  if (t == 0) {
    int c = 0; cum[0] = 0;
    for (int bb = 0; bb < B_; ++bb) { len[bb] = red[bb * 32]; c += red[bb * 32]; cum[bb + 1] = c; }
    meta[0] = c;
    meta[1] = (c + 127) & ~127;
  }
  __syncthreads();
  const int Mv = cum[16];
  for (int i = t; i < MTOK_ + MPADR_; i += 512) {
    int orig;
    if (i < Mv) {
      int bb = 0;
#pragma unroll
      for (int k = 1; k <= 16; ++k) bb += (i >= cum[k]) ? 1 : 0;
      orig = bb * S_ + (i - cum[bb]);
    } else {
      int d = i - Mv;
      orig = MTOK_ + (d < MPADR_ ? d : MPADR_ - 1);
    }
    rowmap[i] = orig;
  }
}

__global__ __launch_bounds__(256) void merge_k(
    const f16* __restrict__ proj, const int* __restrict__ tl,
    float* __restrict__ means, float* __restrict__ masks)
{
  const int w = blockIdx.x, b = blockIdx.y;
  const int t = threadIdx.x;
  __shared__ int red[256];
  int part = 0;
  for (int j = t; j < w; j += 256) part += tl[b * W_ + j];
  red[t] = part; __syncthreads();
  for (int o = 128; o > 0; o >>= 1) { if (t < o) red[t] += red[t + o]; __syncthreads(); }
  const int start = red[0];
  const int len = tl[b * W_ + w];
  float s = 0.f;
  for (int l = 0; l < len; ++l)
    s += (float)proj[((size_t)b * S_ + 1 + start + l) * WD_ + t];
  means[((size_t)b * W_ + w) * WD_ + t] = (len > 0) ? s / (float)len : 0.f;
  if (t == 0) masks[b * W_ + w] = (len > 0) ? 1.f : 0.f;
}

extern "C" void kernel_launch(void* const* d_in, const int* in_sizes, int n_in,
                              void* d_out, int out_size, void* d_ws, size_t ws_size,
                              hipStream_t stream)
{
  (void)in_sizes; (void)n_in; (void)out_size;
  const int*   ids   = (const int*)d_in[0];
  const int*   amask = (const int*)d_in[1];
  const int*   tlens = (const int*)d_in[2];
  const float* wemb  = (const float*)d_in[3];
  const float* pemb  = (const float*)d_in[4];
  const float* temb  = (const float*)d_in[5];
  const float* elns  = (const float*)d_in[6];
  const float* elnb  = (const float*)d_in[7];
  const float* Wq = (const float*)d_in[8];  const float* bq = (const float*)d_in[9];
  const float* Wk = (const float*)d_in[10]; const float* bk = (const float*)d_in[11];
  const float* Wv = (const float*)d_in[12]; const float* bv = (const float*)d_in[13];
  const float* Wo = (const float*)d_in[14]; const float* bo = (const float*)d_in[15];
  const float* l1s = (const float*)d_in[16]; const float* l1b = (const float*)d_in[17];
  const float* W1 = (const float*)d_in[18]; const float* b1 = (const float*)d_in[19];
  const float* W2 = (const float*)d_in[20]; const float* b2 = (const float*)d_in[21];
  const float* l2s = (const float*)d_in[22]; const float* l2b = (const float*)d_in[23];
  const float* pW = (const float*)d_in[24]; const float* pb = (const float*)d_in[25];

  const int MR = MTOK_ + MPADR_;   // rows incl. dummy pad region
  char* ws = (char*)d_ws;
  size_t off = 0;
  auto alloc = [&](size_t n) { void* r = ws + off; off += (n + 255) & ~(size_t)255; return r; };
  f16*   h16   = (f16*)alloc((size_t)MR * H_ * 2);
  f16*   qkv   = (f16*)alloc((size_t)MR * QKVN_ * 2);
  f16*   ctx16 = (f16*)alloc((size_t)MR * H_ * 2);
  f16*   vT    = (f16*)alloc((size_t)B_ * NH_ * DH_ * S_ * 2);
  f16*   ff16  = (f16*)alloc((size_t)MR * FF_ * 2);
  f16*   tmp16 = (f16*)alloc((size_t)MR * H_ * 2 * 2);   // 2 split-K halves
  f16*   projf = (f16*)alloc((size_t)MR * WD_ * 2);
  f16*   pwT   = (f16*)alloc((size_t)WD_ * H_ * 2);
  float* bqkv  = (float*)alloc((size_t)L_ * QKVN_ * 4);
  int*   lenb  = (int*)alloc(256);
  int*   meta  = (int*)alloc(256);
  int*   rowmap = (int*)alloc((size_t)MR * 4);
  f16*   tmp16b = tmp16 + (size_t)MR * H_;

  const size_t wqkv_sz = (size_t)QKVN_ * H_ * 2;
  const size_t wo_sz   = (size_t)H_ * H_ * 2;
  const size_t w1_sz   = (size_t)H_ * FF_ * 2;
  const size_t w2_sz   = (size_t)FF_ * H_ * 2;
  const size_t per_layer_w = wqkv_sz + wo_sz + w1_sz + w2_sz;
  const bool big = ws_size >= off + (size_t)L_ * per_layer_w + 8192;
  const int nz = big ? L_ : 1;
  f16* wqkv0 = (f16*)alloc((size_t)nz * wqkv_sz);
  f16* wo0   = (f16*)alloc((size_t)nz * wo_sz);
  f16* w10   = (f16*)alloc((size_t)nz * w1_sz);
  f16* w20   = (f16*)alloc((size_t)nz * w2_sz);

  lenmap_k<<<1, 512, 0, stream>>>(amask, lenb, meta, rowmap);
  embed_ln_k<<<MTOK_ / 4, 256, 0, stream>>>(ids, wemb, pemb, temb, elns, elnb, h16);
  transpose_f16_k<float><<<dim3(WD_/32, H_/32, 1), 256, 0, stream>>>(pW, pwT, WD_, H_, 0, 0);
  bias_cat_k<<<dim3(QKVN_/256, L_), 256, 0, stream>>>(bq, bk, bv, bqkv);

  if (big) {
    transpose_f16_k<float><<<dim3(H_/32, H_/32, L_), 256, 0, stream>>>(
        Wq, wqkv0,                   H_, H_, (long)H_*H_, (long)QKVN_*H_);
    transpose_f16_k<float><<<dim3(H_/32, H_/32, L_), 256, 0, stream>>>(
        Wk, wqkv0 + (size_t)H_*H_,   H_, H_, (long)H_*H_, (long)QKVN_*H_);
    transpose_f16_k<float><<<dim3(H_/32, H_/32, L_), 256, 0, stream>>>(
        Wv, wqkv0 + (size_t)2*H_*H_, H_, H_, (long)H_*H_, (long)QKVN_*H_);
    transpose_f16_k<float><<<dim3(H_/32, H_/32, L_), 256, 0, stream>>>(
        Wo, wo0, H_, H_, (long)H_*H_, (long)H_*H_);
    transpose_f16_k<float><<<dim3(FF_/32, H_/32, L_), 256, 0, stream>>>(
        W1, w10, FF_, H_, (long)H_*FF_, (long)H_*FF_);
    transpose_f16_k<float><<<dim3(H_/32, FF_/32, L_), 256, 0, stream>>>(
        W2, w20, H_, FF_, (long)FF_*H_, (long)FF_*H_);
  }

  for (int l = 0; l < L_; ++l) {
    f16* wqkv_l = wqkv0 + (size_t)(big ? l : 0) * QKVN_ * H_;
    f16* wo_l   = wo0   + (size_t)(big ? l : 0) * H_ * H_;
    f16* w1_l   = w10   + (size_t)(big ? l : 0) * H_ * FF_;
    f16* w2_l   = w20   + (size_t)(big ? l : 0) * FF_ * H_;
    if (!big) {
      transpose_f16_k<float><<<dim3(H_/32, H_/32, 1), 256, 0, stream>>>(
          Wq + (size_t)l*H_*H_, wqkv_l,                   H_, H_, 0, 0);
      transpose_f16_k<float><<<dim3(H_/32, H_/32, 1), 256, 0, stream>>>(
          Wk + (size_t)l*H_*H_, wqkv_l + (size_t)H_*H_,   H_, H_, 0, 0);
      transpose_f16_k<float><<<dim3(H_/32, H_/32, 1), 256, 0, stream>>>(
          Wv + (size_t)l*H_*H_, wqkv_l + (size_t)2*H_*H_, H_, H_, 0, 0);
      transpose_f16_k<float><<<dim3(H_/32, H_/32, 1), 256, 0, stream>>>(
          Wo + (size_t)l*H_*H_, wo_l, H_, H_, 0, 0);
      transpose_f16_k<float><<<dim3(FF_/32, H_/32, 1), 256, 0, stream>>>(
          W1 + (size_t)l*H_*FF_, w1_l, FF_, H_, 0, 0);
      transpose_f16_k<float><<<dim3(H_/32, FF_/32, 1), 256, 0, stream>>>(
          W2 + (size_t)l*FF_*H_, w2_l, H_, FF_, 0, 0);
    }
    // fused QKV projection (single-buf 128x128); V cols -> vT transposed
    gemm2_k<128,128,0,1,1,1,1,0,0><<<dim3(QKVN_/128, MTOK_/128, 1), 256, 0, stream>>>(
        h16, wqkv_l, qkv, bqkv + (size_t)l*QKVN_, vT, rowmap, meta, H_, H_, QKVN_, H_, 1.0f, 0);
    // fused flash attention (64-q blocks) -> ctx16
    fattn_k<<<dim3(B_*NH_, S_/64), 256, 0, stream>>>(qkv, vT, ctx16, lenb);
    // O projection: 64x64 split-K=2 -> compact tmp16/tmp16b, then LN
    gemm2_k<64,64,0,1,1,0,2,0,1><<<dim3(H_/64, MTOK_/64, 2), 256, 0, stream>>>(
        ctx16, wo_l, tmp16, bo + (size_t)l*H_, nullptr, rowmap, meta, H_, H_, H_, H_, 1.0f, (long)MR * H_);
    ln_res_k<<<MTOK_/4, 256, 0, stream>>>(h16, tmp16, tmp16b, l1s + (size_t)l*H_, l1b + (size_t)l*H_, rowmap, meta);
    // FFN: FF1 single-buf 128x128 -> compact ff16; FF2 64x64 split-K=2 (compact in/out)
    gemm2_k<128,128,1,1,1,0,1,0,1><<<dim3(FF_/128, MTOK_/128, 1), 256, 0, stream>>>(
        h16, w1_l, ff16, b1 + (size_t)l*FF_, nullptr, rowmap, meta, H_, H_, FF_, H_, 1.0f, 0);
    gemm2_k<64,64,0,1,1,0,2,1,1><<<dim3(H_/64, MTOK_/64, 2), 256, 0, stream>>>(
        ff16, w2_l, tmp16, b2 + (size_t)l*H_, nullptr, rowmap, meta, FF_, FF_, H_, FF_, 1.0f, (long)MR * H_);
    ln_res_k<<<MTOK_/4, 256, 0, stream>>>(h16, tmp16, tmp16b, l2s + (size_t)l*H_, l2b + (size_t)l*H_, rowmap, meta);
  }

  // projection to word dims (f16 out, original rows for merge)
  gemm2_k<64,64,0,1,1,0,1,0,0><<<dim3(WD_/64, MTOK_/64, 1), 256, 0, stream>>>(
      h16, pwT, projf, pb, nullptr, rowmap, meta, H_, H_, WD_, H_, 1.0f, 0);
  merge_k<<<dim3(W_, B_), 256, 0, stream>>>(projf, tlens,
      (float*)d_out, (float*)d_out + (size_t)B_ * W_ * WD_);
}

// Round 14
// 2237.633 us; speedup vs baseline: 1.1065x; 1.0096x over previous
//
#include <hip/hip_runtime.h>
#include <stdint.h>

#define B_ 16
#define S_ 512
#define H_ 768
#define L_ 12
#define NH_ 12
#define DH_ 64
#define FF_ 3072
#define WD_ 256
#define W_ 255
#define MTOK_ (B_*S_)
#define QKVN_ 2304
#define MPADR_ 128   // dummy pad rows appended to row-indexed buffers

typedef _Float16 f16;
typedef _Float16 f16x8 __attribute__((ext_vector_type(8)));
typedef _Float16 f16x4 __attribute__((ext_vector_type(4)));
typedef _Float16 f16x2 __attribute__((ext_vector_type(2)));
typedef float f32x4 __attribute__((ext_vector_type(4)));

#define SCHED_FENCE() __builtin_amdgcn_sched_barrier(0)

// tanh-form gelu via exp-sigmoid; max |dev| vs exact ~7e-4 (threshold margin 3x)
__device__ __forceinline__ float gelu_fast(float x) {
  float u = x * (1.0f + 0.044715f * x * x);
  float e = __expf(-1.5957691216f * u);
  return __fdividef(x, 1.0f + e);
}

__device__ __forceinline__ void gload16(const f16* g, f16* l) {
  __builtin_amdgcn_global_load_lds(
      (const __attribute__((address_space(1))) void*)g,
      (__attribute__((address_space(3))) void*)l, 16, 0, 0);
}

// Row-compacted GEMM, SINGLE-buffered m97 structure. SPLITK>1: blockIdx.z is
// the K-chunk; chunk z writes (f16*)Cv + z*czoff; bias only on z=0.
// CIN=1: A rows are compact (no rowmap gather). COUT=1: C rows written at the
// compact index (contiguous). Early exit on ORIGINAL flat id (dead tail
// XCD-balanced), bijective XCD swizzle within live count.
// QKVW=1: cols >= 2*H_ -> vT[bh][d][s]; other cols -> Cv at ORIGINAL rows.
template<int BM, int BN, int ACT, int OUTF16, int BIAS, int QKVW, int SPLITK, int CIN, int COUT>
__global__ __launch_bounds__(256) void gemm2_k(
    const f16* __restrict__ A, const f16* __restrict__ Bm, void* __restrict__ Cv,
    const float* __restrict__ bias, f16* __restrict__ vTp,
    const int* __restrict__ rowmap, const int* __restrict__ meta,
    int lda, int ldb, int ldc, int K, float scale, long czoff)
{
  constexpr int MI = BM / 32;
  constexpr int NI = BN / 32;
  const int gx = gridDim.x;
  int flat = blockIdx.y * gx + blockIdx.x;
  const int nlive = (meta[1] / BM) * gx;
  if (flat >= nlive) return;                // uniform: whole block exits pre-barrier
  {
    int q = nlive >> 3, r = nlive & 7;
    int xcd = flat & 7, idx = flat >> 3;
    flat = (xcd < r ? xcd * (q + 1) : r * (q + 1) + (xcd - r) * q) + idx;
  }
  const int row0 = (flat / gx) * BM;
  const int col0 = (flat % gx) * BN;
  const int z = (SPLITK > 1) ? blockIdx.z : 0;
  const int kc_len = K / SPLITK;
  A  += (size_t)z * kc_len;
  Bm += (size_t)z * kc_len;

  __shared__ __align__(16) f16 lA[BM * 64];
  __shared__ __align__(16) f16 lB[BN * 64];
  const int lane = threadIdx.x & 63;
  const int wave = threadIdx.x >> 6;
  const int wr = wave >> 1, wc = wave & 1;
  const int srow = lane >> 3;
  const int scol = lane & 7;
  const int cs = scol ^ srow;

  int arow[BM / 32];
#pragma unroll
  for (int i = 0; i < BM / 32; ++i) {
    int cr = row0 + (wave * (BM / 32) + i) * 8 + srow;
    arow[i] = CIN ? cr : rowmap[cr];
  }

  f32x4 acc[MI][NI] = {};
  const int nt = kc_len >> 6;
  const int rl = lane & 15, g = lane >> 4;
  for (int t = 0; t < nt; ++t) {
    __syncthreads();                        // all waves done reading previous tile
    const int k0 = t * 64;
#pragma unroll
    for (int i = 0; i < BM / 32; ++i) {
      int seg = wave * (BM / 32) + i;
      gload16(&A[(size_t)arow[i] * lda + k0 + cs * 8], &lA[seg * 512]);
    }
#pragma unroll
    for (int i = 0; i < BN / 32; ++i) {
      int seg = wave * (BN / 32) + i;
      gload16(&Bm[(size_t)(col0 + seg * 8 + srow) * ldb + k0 + cs * 8], &lB[seg * 512]);
    }
    __syncthreads();                        // drains vmcnt(0): tile landed
#pragma unroll
    for (int c = 0; c < 2; ++c) {
      f16x8 af[MI], bf[NI];
#pragma unroll
      for (int mi = 0; mi < MI; ++mi) {
        int r = wr * (MI * 16) + mi * 16 + rl;
        int u = (c * 4 + g) ^ (r & 7);
        af[mi] = *(const f16x8*)&lA[r * 64 + u * 8];
      }
#pragma unroll
      for (int ni = 0; ni < NI; ++ni) {
        int r = wc * (NI * 16) + ni * 16 + rl;
        int u = (c * 4 + g) ^ (r & 7);
        bf[ni] = *(const f16x8*)&lB[r * 64 + u * 8];
      }
#pragma unroll
      for (int mi = 0; mi < MI; ++mi)
#pragma unroll
        for (int ni = 0; ni < NI; ++ni)
          acc[mi][ni] = __builtin_amdgcn_mfma_f32_16x16x32_f16(af[mi], bf[ni], acc[mi][ni], 0, 0, 0);
    }
  }
  // epilogue: C/D layout col=lane&15, row=(lane>>4)*4+reg
  const int cl = lane & 15;
  const int rq = (lane >> 4) * 4;
#pragma unroll
  for (int mi = 0; mi < MI; ++mi) {
    const int crow0 = row0 + wr * (MI * 16) + mi * 16 + rq;
    int rows[4];
    bool contig;
    if constexpr (COUT && !QKVW) {
#pragma unroll
      for (int r = 0; r < 4; ++r) rows[r] = crow0 + r;
      contig = true;
    } else {
      const int4 rm4 = *(const int4*)&rowmap[crow0];
      rows[0] = rm4.x; rows[1] = rm4.y; rows[2] = rm4.z; rows[3] = rm4.w;
      contig = (rm4.w == rm4.x + 3) && ((rm4.x & 3) == 0);
    }
    (void)contig;
#pragma unroll
    for (int ni = 0; ni < NI; ++ni) {
      int col = col0 + wc * (NI * 16) + ni * 16 + cl;
      float bv = 0.f;
      if constexpr (BIAS) { if (SPLITK == 1 || z == 0) bv = bias[col]; }
      if constexpr (QKVW) {
        if (col >= 2 * H_) {                 // transposed V write: vT[bh][d][s]
          int vc = col - 2 * H_;
          int h = vc >> 6, d = vc & 63;
          if (contig) {
            if (rows[0] < MTOK_) {
              int b = rows[0] >> 9, s = rows[0] & (S_ - 1);
              f16x4 o4;
#pragma unroll
              for (int r = 0; r < 4; ++r) o4[r] = (f16)(acc[mi][ni][r] * scale + bv);
              *(f16x4*)&vTp[(((size_t)(b * NH_ + h)) * DH_ + d) * S_ + s] = o4;
            }
          } else {
#pragma unroll
            for (int r = 0; r < 4; ++r) {
              int orow = rows[r];
              if (orow < MTOK_) {
                int b = orow >> 9, s = orow & (S_ - 1);
                vTp[(((size_t)(b * NH_ + h)) * DH_ + d) * S_ + s] = (f16)(acc[mi][ni][r] * scale + bv);
              }
            }
          }
          continue;
        }
      }
#pragma unroll
      for (int r = 0; r < 4; ++r) {
        float v = acc[mi][ni][r] * scale + bv;
        if constexpr (ACT == 1) v = gelu_fast(v);
        if constexpr (OUTF16) {
          ((f16*)Cv + (size_t)z * czoff)[(size_t)rows[r] * ldc + col] = (f16)v;
        } else {
          ((float*)Cv)[(size_t)rows[r] * ldc + col] = v;
        }
      }
    }
  }
}

// Fused flash attention, 64-q-row blocks (wave owns 16 q rows). Issue-early
// staging + counted vmcnt. grid (b*NH, qtile of 64). Swapped QK^T -> S^T acc.
// No-max softmax (Q pre-scaled by 1/8; masked kv -> exact 0). Output scattered
// to COMPACT ctx rows via cmap (dead q rows land in the pad region).
__global__ __launch_bounds__(256) void fattn_k(
    const f16* __restrict__ qkv, const f16* __restrict__ vT,
    f16* __restrict__ ctx, const int* __restrict__ lenp, const int* __restrict__ cmap)
{
  const int bh = blockIdx.x, qt = blockIdx.y;
  const int b = bh / NH_, h = bh - b * NH_;
  const int L = lenp[b];
  if ((qt << 6) >= L) return;               // uniform per block
  const int nkt = (L + 63) >> 6;
  const int lane = threadIdx.x & 63, wave = threadIdx.x >> 6;
  const int rl = lane & 15, g = lane >> 4;
  const int srow = lane >> 3, scol = lane & 7;
  const int cs = scol ^ srow;

  __shared__ __align__(16) f16 lK[2][64 * 64];
  __shared__ __align__(16) f16 lV[2][64 * 64];
  __shared__ __align__(16) f16 lP[64 * 72];

  auto stage = [&](int p, int kt) {       // 4 gload16 per wave
#pragma unroll
    for (int i = 0; i < 2; ++i) {
      int seg = wave * 2 + i;
      int r = seg * 8 + srow;
      gload16(&qkv[((size_t)b * S_ + kt * 64 + r) * QKVN_ + H_ + h * DH_ + cs * 8], &lK[p][seg * 512]);
      gload16(&vT[((size_t)bh * DH_ + r) * S_ + kt * 64 + cs * 8], &lV[p][seg * 512]);
    }
  };

  const size_t qrow0 = (size_t)b * S_ + qt * 64 + wave * 16;
  f16x8 qf[2];
#pragma unroll
  for (int kc = 0; kc < 2; ++kc) {
    qf[kc] = *(const f16x8*)&qkv[(qrow0 + rl) * QKVN_ + h * DH_ + kc * 32 + g * 8];
    qf[kc] *= (f16)0.125f;                  // exact pow2 scale: scores = (Q/8)K
  }

  float lsum = 0.f;
  f32x4 accO[4] = {};

  stage(0, 0);
  for (int kt = 0; kt < nkt; ++kt) {
    if (kt + 1 < nkt) {
      stage((kt + 1) & 1, kt + 1);
      asm volatile("s_waitcnt vmcnt(4) lgkmcnt(0)" ::: "memory");
    } else {
      asm volatile("s_waitcnt vmcnt(0) lgkmcnt(0)" ::: "memory");
    }
    SCHED_FENCE();
    __builtin_amdgcn_s_barrier();           // B1: all stage(kt) complete
    SCHED_FENCE();
    const int p = kt & 1;

    f32x4 accS[4] = {};
    __builtin_amdgcn_s_setprio(1);
#pragma unroll
    for (int kc = 0; kc < 2; ++kc) {
#pragma unroll
      for (int ak = 0; ak < 4; ++ak) {
        int row = ak * 16 + rl;
        int u = (kc * 4 + g) ^ (row & 7);
        f16x8 kf = *(const f16x8*)&lK[p][row * 64 + u * 8];
        accS[ak] = __builtin_amdgcn_mfma_f32_16x16x32_f16(kf, qf[kc], accS[ak], 0, 0, 0);
      }
    }
    __builtin_amdgcn_s_setprio(0);

    const int kvb = kt * 64 + g * 4;
    {
      float pv[16];
      float ps = 0.f;
#pragma unroll
      for (int ak = 0; ak < 4; ++ak)
#pragma unroll
        for (int r = 0; r < 4; ++r) {
          float pp = (kvb + ak * 16 + r < L) ? __expf(accS[ak][r]) : 0.f;
          pv[ak * 4 + r] = pp;
          ps += pp;
        }
      ps += __shfl_xor(ps, 16);
      ps += __shfl_xor(ps, 32);
      lsum += ps;
      const int qrow = wave * 16 + rl;
#pragma unroll
      for (int ak = 0; ak < 4; ++ak)
#pragma unroll
        for (int r2 = 0; r2 < 2; ++r2) {
          f16x2 pk = { (f16)pv[ak * 4 + r2 * 2], (f16)pv[ak * 4 + r2 * 2 + 1] };
          *(f16x2*)&lP[qrow * 72 + ak * 16 + g * 4 + r2 * 2] = pk;
        }
    }
    __builtin_amdgcn_s_setprio(1);
#pragma unroll
    for (int kc = 0; kc < 2; ++kc) {
      f16x8 pa = *(const f16x8*)&lP[(wave * 16 + rl) * 72 + kc * 32 + g * 8];
      f16x8 vf[4];
#pragma unroll
      for (int bd = 0; bd < 4; ++bd) {
        int vrow = bd * 16 + rl;
        int u = (kc * 4 + g) ^ (vrow & 7);
        vf[bd] = *(const f16x8*)&lV[p][vrow * 64 + u * 8];
      }
#pragma unroll
      for (int bd = 0; bd < 4; ++bd)
        accO[bd] = __builtin_amdgcn_mfma_f32_16x16x32_f16(pa, vf[bd], accO[bd], 0, 0, 0);
    }
    __builtin_amdgcn_s_setprio(0);
    SCHED_FENCE();
    asm volatile("s_waitcnt lgkmcnt(0)" ::: "memory");
    SCHED_FENCE();
    __builtin_amdgcn_s_barrier();           // B2: all reads of buf[kt&1] done
    SCHED_FENCE();
  }

  float linv = 1.f / lsum;
  const int orow0 = b * S_ + qt * 64 + wave * 16;
#pragma unroll
  for (int r = 0; r < 4; ++r) {
    float li = __shfl(linv, (lane & 48) | (g * 4 + r));
    int q = g * 4 + r;
    int crow = cmap[orow0 + q];
#pragma unroll
    for (int bd = 0; bd < 4; ++bd)
      ctx[(size_t)crow * H_ + h * DH_ + bd * 16 + rl] = (f16)(accO[bd][r] * li);
  }
}

// out[n*ldout + k] = (f16) in[k*ldin + n]; 32x32 tiles, batched via z.
template<typename TI>
__global__ __launch_bounds__(256) void transpose_f16_k(
    const TI* __restrict__ in, f16* __restrict__ out,
    int ldin, int ldout, long i1, long o1)
{
  const int z = blockIdx.z;
  in  += (size_t)z * i1;
  out += (size_t)z * o1;
  __shared__ float t[32][33];
  const int kt = blockIdx.y * 32, nt = blockIdx.x * 32;
  const int tx = threadIdx.x & 31, tg = threadIdx.x >> 5;
#pragma unroll
  for (int i = 0; i < 4; ++i) {
    int k = tg * 4 + i;
    t[k][tx] = (float)in[(size_t)(kt + k) * ldin + nt + tx];
  }
  __syncthreads();
#pragma unroll
  for (int i = 0; i < 4; ++i) {
    int n = tg * 4 + i;
    out[(size_t)(nt + n) * ldout + kt + tx] = (f16)t[tx][n];
  }
}

__global__ void bias_cat_k(const float* __restrict__ bq, const float* __restrict__ bk,
                           const float* __restrict__ bv, float* __restrict__ out) {
  const int l = blockIdx.y;
  const int j = blockIdx.x * 256 + threadIdx.x;
  float v = (j < H_) ? bq[l * H_ + j] : (j < 2 * H_) ? bk[l * H_ + j - H_] : bv[l * H_ + j - 2 * H_];
  out[l * QKVN_ + j] = v;
}

// embed + LN -> h16 at COMPACT rows (gathers orig row via rowmap)
__global__ __launch_bounds__(256) void embed_ln_k(
    const int* __restrict__ ids, const float* __restrict__ wemb,
    const float* __restrict__ pemb, const float* __restrict__ temb,
    const float* __restrict__ lns, const float* __restrict__ lnb,
    f16* __restrict__ h16, const int* __restrict__ rowmap, const int* __restrict__ meta)
{
  const int crow = blockIdx.x * 4 + (threadIdx.x >> 6);
  if (crow >= meta[0]) return;
  const int row = rowmap[crow];
  const int lane = threadIdx.x & 63;
  const int s = row & (S_ - 1);
  const float4* wp = (const float4*)(wemb + (size_t)ids[row] * H_);
  const float4* pp = (const float4*)(pemb + (size_t)s * H_);
  const float4* tp = (const float4*)temb;
  float4 x[3]; float sm = 0.f, sq = 0.f;
#pragma unroll
  for (int j = 0; j < 3; ++j) {
    int i4 = lane + 64 * j;
    float4 a = wp[i4], bb = pp[i4], c = tp[i4];
    float4 v; v.x = a.x + bb.x + c.x; v.y = a.y + bb.y + c.y;
    v.z = a.z + bb.z + c.z; v.w = a.w + bb.w + c.w;
    x[j] = v;
    sm += v.x + v.y + v.z + v.w;
    sq += v.x * v.x + v.y * v.y + v.z * v.z + v.w * v.w;
  }
#pragma unroll
  for (int o = 32; o > 0; o >>= 1) { sm += __shfl_xor(sm, o); sq += __shfl_xor(sq, o); }
  float mean = sm * (1.f / H_);
  float inv = rsqrtf(sq * (1.f / H_) - mean * mean + 1e-12f);
  f16* ho = h16 + (size_t)crow * H_;
#pragma unroll
  for (int j = 0; j < 3; ++j) {
    int i4 = lane + 64 * j;
    float4 sc = ((const float4*)lns)[i4], bi = ((const float4*)lnb)[i4];
    float4 v = x[j];
    f16x4 o4 = {(f16)((v.x - mean) * inv * sc.x + bi.x),
                (f16)((v.y - mean) * inv * sc.y + bi.y),
                (f16)((v.z - mean) * inv * sc.z + bi.z),
                (f16)((v.w - mean) * inv * sc.w + bi.w)};
    *(f16x4*)&ho[i4 * 4] = o4;
  }
}

// fully-compact residual(h16 + tmpA + tmpB) -> LN -> h16
__global__ __launch_bounds__(256) void ln_res_k(
    f16* __restrict__ h16, const f16* __restrict__ tmpA, const f16* __restrict__ tmpB,
    const float* __restrict__ lns, const float* __restrict__ lnb,
    const int* __restrict__ meta)
{
  const int crow = blockIdx.x * 4 + (threadIdx.x >> 6);
  if (crow >= meta[0]) return;
  const int lane = threadIdx.x & 63;
  const f16x4* hp = (const f16x4*)(h16 + (size_t)crow * H_);
  const f16x4* ta = (const f16x4*)(tmpA + (size_t)crow * H_);
  const f16x4* tb = (const f16x4*)(tmpB + (size_t)crow * H_);
  float4 x[3]; float sm = 0.f, sq = 0.f;
#pragma unroll
  for (int j = 0; j < 3; ++j) {
    int i4 = lane + 64 * j;
    f16x4 a = hp[i4], va = ta[i4], vb = tb[i4];
    float4 v;
    v.x = (float)a[0] + (float)va[0] + (float)vb[0];
    v.y = (float)a[1] + (float)va[1] + (float)vb[1];
    v.z = (float)a[2] + (float)va[2] + (float)vb[2];
    v.w = (float)a[3] + (float)va[3] + (float)vb[3];
    x[j] = v;
    sm += v.x + v.y + v.z + v.w;
    sq += v.x * v.x + v.y * v.y + v.z * v.z + v.w * v.w;
  }
#pragma unroll
  for (int o = 32; o > 0; o >>= 1) { sm += __shfl_xor(sm, o); sq += __shfl_xor(sq, o); }
  float mean = sm * (1.f / H_);
  float inv = rsqrtf(sq * (1.f / H_) - mean * mean + 1e-12f);
  f16* ho = h16 + (size_t)crow * H_;
#pragma unroll
  for (int j = 0; j < 3; ++j) {
    int i4 = lane + 64 * j;
    float4 sc = ((const float4*)lns)[i4], bi = ((const float4*)lnb)[i4];
    float4 v = x[j];
    f16x4 o4 = {(f16)((v.x - mean) * inv * sc.x + bi.x),
                (f16)((v.y - mean) * inv * sc.y + bi.y),
                (f16)((v.z - mean) * inv * sc.z + bi.z),
                (f16)((v.w - mean) * inv * sc.w + bi.w)};
    *(f16x4*)&ho[i4 * 4] = o4;
  }
}

// fused: per-batch lengths, meta {Mv, Mpad, cum[0..16]}, compact->orig rowmap,
// and orig->compact cmap (dead orig rows -> spread into pad region)
__global__ void lenmap_k(const int* __restrict__ mask, int* __restrict__ len,
                         int* __restrict__ meta, int* __restrict__ rowmap,
                         int* __restrict__ cmap) {
  const int t = threadIdx.x;   // 512
  __shared__ int red[512];
  __shared__ int cum[17];
  const int b = t >> 5, sl = t & 31;   // 32 lanes per batch
  int part = 0;
#pragma unroll
  for (int j = 0; j < 16; ++j) part += mask[b * S_ + sl + 32 * j];
  red[t] = part; __syncthreads();
  for (int o = 16; o > 0; o >>= 1) {
    if (sl < o) red[t] += red[t + o];
    __syncthreads();
  }
  if (t == 0) {
    int c = 0; cum[0] = 0;
    for (int bb = 0; bb < B_; ++bb) { len[bb] = red[bb * 32]; c += red[bb * 32]; cum[bb + 1] = c; }
    meta[0] = c;
    meta[1] = (c + 127) & ~127;
    for (int k = 0; k <= 16; ++k) meta[2 + k] = cum[k];
  }
  __syncthreads();
  const int Mv = cum[16];
  for (int i = t; i < MTOK_ + MPADR_; i += 512) {
    int orig;
    if (i < Mv) {
      int bb = 0;
#pragma unroll
      for (int k = 1; k <= 16; ++k) bb += (i >= cum[k]) ? 1 : 0;
      orig = bb * S_ + (i - cum[bb]);
    } else {
      int d = i - Mv;
      orig = MTOK_ + (d < MPADR_ ? d : MPADR_ - 1);
    }
    rowmap[i] = orig;
  }
  for (int i = t; i < MTOK_; i += 512) {
    int bb = i >> 9, s = i & (S_ - 1);
    int lb = cum[bb + 1] - cum[bb];
    cmap[i] = (s < lb) ? (cum[bb] + s) : (Mv + (i & 127));
  }
}

// means over compact proj rows: row(b, s) -> cum[b] + s
__global__ __launch_bounds__(256) void merge_k(
    const f16* __restrict__ proj, const int* __restrict__ tl,
    const int* __restrict__ meta,
    float* __restrict__ means, float* __restrict__ masks)
{
  const int w = blockIdx.x, b = blockIdx.y;
  const int t = threadIdx.x;
  __shared__ int red[256];
  int part = 0;
  for (int j = t; j < w; j += 256) part += tl[b * W_ + j];
  red[t] = part; __syncthreads();
  for (int o = 128; o > 0; o >>= 1) { if (t < o) red[t] += red[t + o]; __syncthreads(); }
  const int start = red[0];
  const int len = tl[b * W_ + w];
  const int base = meta[2 + b] + 1 + start;   // compact row of first wordpiece
  float s = 0.f;
  for (int l = 0; l < len; ++l)
    s += (float)proj[((size_t)(base + l)) * WD_ + t];
  means[((size_t)b * W_ + w) * WD_ + t] = (len > 0) ? s / (float)len : 0.f;
  if (t == 0) masks[b * W_ + w] = (len > 0) ? 1.f : 0.f;
}

extern "C" void kernel_launch(void* const* d_in, const int* in_sizes, int n_in,
                              void* d_out, int out_size, void* d_ws, size_t ws_size,
                              hipStream_t stream)
{
  (void)in_sizes; (void)n_in; (void)out_size;
  const int*   ids   = (const int*)d_in[0];
  const int*   amask = (const int*)d_in[1];
  const int*   tlens = (const int*)d_in[2];
  const float* wemb  = (const float*)d_in[3];
  const float* pemb  = (const float*)d_in[4];
  const float* temb  = (const float*)d_in[5];
  const float* elns  = (const float*)d_in[6];
  const float* elnb  = (const float*)d_in[7];
  const float* Wq = (const float*)d_in[8];  const float* bq = (const float*)d_in[9];
  const float* Wk = (const float*)d_in[10]; const float* bk = (const float*)d_in[11];
  const float* Wv = (const float*)d_in[12]; const float* bv = (const float*)d_in[13];
  const float* Wo = (const float*)d_in[14]; const float* bo = (const float*)d_in[15];
  const float* l1s = (const float*)d_in[16]; const float* l1b = (const float*)d_in[17];
  const float* W1 = (const float*)d_in[18]; const float* b1 = (const float*)d_in[19];
  const float* W2 = (const float*)d_in[20]; const float* b2 = (const float*)d_in[21];
  const float* l2s = (const float*)d_in[22]; const float* l2b = (const float*)d_in[23];
  const float* pW = (const float*)d_in[24]; const float* pb = (const float*)d_in[25];

  const int MR = MTOK_ + MPADR_;   // rows incl. dummy pad region
  char* ws = (char*)d_ws;
  size_t off = 0;
  auto alloc = [&](size_t n) { void* r = ws + off; off += (n + 255) & ~(size_t)255; return r; };
  f16*   h16   = (f16*)alloc((size_t)MR * H_ * 2);
  f16*   qkv   = (f16*)alloc((size_t)MR * QKVN_ * 2);
  f16*   ctx16 = (f16*)alloc((size_t)MR * H_ * 2);
  f16*   vT    = (f16*)alloc((size_t)B_ * NH_ * DH_ * S_ * 2);
  f16*   ff16  = (f16*)alloc((size_t)MR * FF_ * 2);
  f16*   tmp16 = (f16*)alloc((size_t)MR * H_ * 2 * 2);   // 2 split-K halves
  f16*   projf = (f16*)alloc((size_t)MR * WD_ * 2);
  f16*   pwT   = (f16*)alloc((size_t)WD_ * H_ * 2);
  float* bqkv  = (float*)alloc((size_t)L_ * QKVN_ * 4);
  int*   lenb  = (int*)alloc(256);
  int*   meta  = (int*)alloc(256);
  int*   rowmap = (int*)alloc((size_t)MR * 4);
  int*   cmap  = (int*)alloc((size_t)MTOK_ * 4);
  f16*   tmp16b = tmp16 + (size_t)MR * H_;

  const size_t wqkv_sz = (size_t)QKVN_ * H_ * 2;
  const size_t wo_sz   = (size_t)H_ * H_ * 2;
  const size_t w1_sz   = (size_t)H_ * FF_ * 2;
  const size_t w2_sz   = (size_t)FF_ * H_ * 2;
  const size_t per_layer_w = wqkv_sz + wo_sz + w1_sz + w2_sz;
  const bool big = ws_size >= off + (size_t)L_ * per_layer_w + 8192;
  const int nz = big ? L_ : 1;
  f16* wqkv0 = (f16*)alloc((size_t)nz * wqkv_sz);
  f16* wo0   = (f16*)alloc((size_t)nz * wo_sz);
  f16* w10   = (f16*)alloc((size_t)nz * w1_sz);
  f16* w20   = (f16*)alloc((size_t)nz * w2_sz);

  lenmap_k<<<1, 512, 0, stream>>>(amask, lenb, meta, rowmap, cmap);
  embed_ln_k<<<MTOK_ / 4, 256, 0, stream>>>(ids, wemb, pemb, temb, elns, elnb, h16, rowmap, meta);
  transpose_f16_k<float><<<dim3(WD_/32, H_/32, 1), 256, 0, stream>>>(pW, pwT, WD_, H_, 0, 0);
  bias_cat_k<<<dim3(QKVN_/256, L_), 256, 0, stream>>>(bq, bk, bv, bqkv);

  if (big) {
    transpose_f16_k<float><<<dim3(H_/32, H_/32, L_), 256, 0, stream>>>(
        Wq, wqkv0,                   H_, H_, (long)H_*H_, (long)QKVN_*H_);
    transpose_f16_k<float><<<dim3(H_/32, H_/32, L_), 256, 0, stream>>>(
        Wk, wqkv0 + (size_t)H_*H_,   H_, H_, (long)H_*H_, (long)QKVN_*H_);
    transpose_f16_k<float><<<dim3(H_/32, H_/32, L_), 256, 0, stream>>>(
        Wv, wqkv0 + (size_t)2*H_*H_, H_, H_, (long)H_*H_, (long)QKVN_*H_);
    transpose_f16_k<float><<<dim3(H_/32, H_/32, L_), 256, 0, stream>>>(
        Wo, wo0, H_, H_, (long)H_*H_, (long)H_*H_);
    transpose_f16_k<float><<<dim3(FF_/32, H_/32, L_), 256, 0, stream>>>(
        W1, w10, FF_, H_, (long)H_*FF_, (long)H_*FF_);
    transpose_f16_k<float><<<dim3(H_/32, FF_/32, L_), 256, 0, stream>>>(
        W2, w20, H_, FF_, (long)FF_*H_, (long)FF_*H_);
  }

  for (int l = 0; l < L_; ++l) {
    f16* wqkv_l = wqkv0 + (size_t)(big ? l : 0) * QKVN_ * H_;
    f16* wo_l   = wo0   + (size_t)(big ? l : 0) * H_ * H_;
    f16* w1_l   = w10   + (size_t)(big ? l : 0) * H_ * FF_;
    f16* w2_l   = w20   + (size_t)(big ? l : 0) * FF_ * H_;
    if (!big) {
      transpose_f16_k<float><<<dim3(H_/32, H_/32, 1), 256, 0, stream>>>(
          Wq + (size_t)l*H_*H_, wqkv_l,                   H_, H_, 0, 0);
      transpose_f16_k<float><<<dim3(H_/32, H_/32, 1), 256, 0, stream>>>(
          Wk + (size_t)l*H_*H_, wqkv_l + (size_t)H_*H_,   H_, H_, 0, 0);
      transpose_f16_k<float><<<dim3(H_/32, H_/32, 1), 256, 0, stream>>>(
          Wv + (size_t)l*H_*H_, wqkv_l + (size_t)2*H_*H_, H_, H_, 0, 0);
      transpose_f16_k<float><<<dim3(H_/32, H_/32, 1), 256, 0, stream>>>(
          Wo + (size_t)l*H_*H_, wo_l, H_, H_, 0, 0);
      transpose_f16_k<float><<<dim3(FF_/32, H_/32, 1), 256, 0, stream>>>(
          W1 + (size_t)l*H_*FF_, w1_l, FF_, H_, 0, 0);
      transpose_f16_k<float><<<dim3(H_/32, FF_/32, 1), 256, 0, stream>>>(
          W2 + (size_t)l*FF_*H_, w2_l, H_, FF_, 0, 0);
    }
    // fused QKV projection (A compact); qkv/vT written at ORIGINAL rows
    gemm2_k<128,128,0,1,1,1,1,1,0><<<dim3(QKVN_/128, MTOK_/128, 1), 256, 0, stream>>>(
        h16, wqkv_l, qkv, bqkv + (size_t)l*QKVN_, vT, rowmap, meta, H_, H_, QKVN_, H_, 1.0f, 0);
    // fused flash attention (64-q blocks) -> compact ctx16 via cmap
    fattn_k<<<dim3(B_*NH_, S_/64), 256, 0, stream>>>(qkv, vT, ctx16, lenb, cmap);
    // O projection: compact in/out, 64x64 split-K=2 -> tmp16/tmp16b, then LN
    gemm2_k<64,64,0,1,1,0,2,1,1><<<dim3(H_/64, MTOK_/64, 2), 256, 0, stream>>>(
        ctx16, wo_l, tmp16, bo + (size_t)l*H_, nullptr, rowmap, meta, H_, H_, H_, H_, 1.0f, (long)MR * H_);
    ln_res_k<<<MTOK_/4, 256, 0, stream>>>(h16, tmp16, tmp16b, l1s + (size_t)l*H_, l1b + (size_t)l*H_, meta);
    // FFN: FF1 compact in/out 128x128; FF2 compact in/out 64x64 split-K=2
    gemm2_k<128,128,1,1,1,0,1,1,1><<<dim3(FF_/128, MTOK_/128, 1), 256, 0, stream>>>(
        h16, w1_l, ff16, b1 + (size_t)l*FF_, nullptr, rowmap, meta, H_, H_, FF_, H_, 1.0f, 0);
    gemm2_k<64,64,0,1,1,0,2,1,1><<<dim3(H_/64, MTOK_/64, 2), 256, 0, stream>>>(
        ff16, w2_l, tmp16, b2 + (size_t)l*H_, nullptr, rowmap, meta, FF_, FF_, H_, FF_, 1.0f, (long)MR * H_);
    ln_res_k<<<MTOK_/4, 256, 0, stream>>>(h16, tmp16, tmp16b, l2s + (size_t)l*H_, l2b + (size_t)l*H_, meta);
  }

  // projection to word dims (compact in/out); merge indexes compact rows
  gemm2_k<64,64,0,1,1,0,1,1,1><<<dim3(WD_/64, MTOK_/64, 1), 256, 0, stream>>>(
      h16, pwT, projf, pb, nullptr, rowmap, meta, H_, H_, WD_, H_, 1.0f, 0);
  merge_k<<<dim3(W_, B_), 256, 0, stream>>>(projf, tlens, meta,
      (float*)d_out, (float*)d_out + (size_t)B_ * W_ * WD_);
}